// Round 1
// baseline (3603.296 us; speedup 1.0000x reference)
//
#include <hip/hip_runtime.h>
#include <math.h>

#define T_DIM 2048
#define C_DIM 1024
#define H_DIM 16
#define HD 64
#define TOPK_K 64

// ---------------- GEMM: C = A[M][K] @ B[N][K]^T ----------------
#define BM 64
#define BN 64
#define BK 16
#define LDSP (BM + 4)

// mode 0: scatter qkv into head-major q/k/v [H][T][64]
// mode 1: silu epilogue, row-major C0[M][N]
// mode 2: plain row-major C0[M][N]
__global__ __launch_bounds__(256) void gemm_kernel(
    const float* __restrict__ A, const float* __restrict__ B,
    float* __restrict__ C0, float* __restrict__ C1, float* __restrict__ C2,
    int M, int N, int K, int mode)
{
  __shared__ float As[BK][LDSP];
  __shared__ float Bs[BK][LDSP];
  const int tid = threadIdx.x;
  const int m0 = blockIdx.y * BM, n0 = blockIdx.x * BN;
  const int tm = tid >> 4, tn = tid & 15;
  const int lr = tid >> 2, lc = (tid & 3) << 2;
  float acc[4][4] = {};
  const float* Aptr = A + (size_t)(m0 + lr) * K + lc;
  const float* Bptr = B + (size_t)(n0 + lr) * K + lc;
  for (int k0 = 0; k0 < K; k0 += BK) {
    float4 av = *(const float4*)(Aptr + k0);
    float4 bv = *(const float4*)(Bptr + k0);
    As[lc + 0][lr] = av.x; As[lc + 1][lr] = av.y;
    As[lc + 2][lr] = av.z; As[lc + 3][lr] = av.w;
    Bs[lc + 0][lr] = bv.x; Bs[lc + 1][lr] = bv.y;
    Bs[lc + 2][lr] = bv.z; Bs[lc + 3][lr] = bv.w;
    __syncthreads();
#pragma unroll
    for (int kk = 0; kk < BK; ++kk) {
      float4 a4 = *(const float4*)&As[kk][tm << 2];
      float4 b4 = *(const float4*)&Bs[kk][tn << 2];
      float a[4] = {a4.x, a4.y, a4.z, a4.w};
      float b[4] = {b4.x, b4.y, b4.z, b4.w};
#pragma unroll
      for (int i = 0; i < 4; ++i)
#pragma unroll
        for (int j = 0; j < 4; ++j)
          acc[i][j] = fmaf(a[i], b[j], acc[i][j]);
    }
    __syncthreads();
  }
  if (mode == 0) {
    const int which = n0 >> 10;          // 0=q 1=k 2=v
    const int h = (n0 & 1023) >> 6;      // head (n0 is 64-aligned)
    float* dst = (which == 0) ? C0 : (which == 1) ? C1 : C2;
#pragma unroll
    for (int i = 0; i < 4; ++i) {
      int m = m0 + (tm << 2) + i;
      float4 o = {acc[i][0], acc[i][1], acc[i][2], acc[i][3]};
      *(float4*)(dst + (((size_t)(h * T_DIM + m)) << 6) + (tn << 2)) = o;
    }
  } else if (mode == 1) {
#pragma unroll
    for (int i = 0; i < 4; ++i) {
      int m = m0 + (tm << 2) + i;
      float4 o;
      float* po = &o.x;
#pragma unroll
      for (int j = 0; j < 4; ++j) {
        float vv = acc[i][j];
        po[j] = vv / (1.f + expf(-vv));   // silu
      }
      *(float4*)(C0 + (size_t)m * N + n0 + (tn << 2)) = o;
    }
  } else {
#pragma unroll
    for (int i = 0; i < 4; ++i) {
      int m = m0 + (tm << 2) + i;
      float4 o = {acc[i][0], acc[i][1], acc[i][2], acc[i][3]};
      *(float4*)(C0 + (size_t)m * N + n0 + (tn << 2)) = o;
    }
  }
}

// ---------------- RoPE in-place on head-major q,k ----------------
__global__ void rope_kernel(float* __restrict__ q, float* __restrict__ k) {
  int idx = blockIdx.x * blockDim.x + threadIdx.x;
  if (idx >= H_DIM * T_DIM * 32) return;
  int d = idx & 31;
  int t = (idx >> 5) & (T_DIM - 1);
  int h = idx >> 16;
  size_t base = ((size_t)(h * T_DIM + t)) << 6;
  double invf = exp(-(double)d * (log(10000.0) / 32.0));
  double ang = (double)t * invf;
  double cs = cos(ang), sn = sin(ang);
  float q1 = q[base + d], q2 = q[base + d + 32];
  q[base + d]      = (float)((double)q1 * cs - (double)q2 * sn);
  q[base + d + 32] = (float)((double)q2 * cs + (double)q1 * sn);
  float k1 = k[base + d], k2 = k[base + d + 32];
  k[base + d]      = (float)((double)k1 * cs - (double)k2 * sn);
  k[base + d + 32] = (float)((double)k2 * cs + (double)k1 * sn);
}

// ---------------- attention ----------------
__device__ __forceinline__ unsigned f2u(float f) {
  unsigned u = __float_as_uint(f);
  return (u & 0x80000000u) ? ~u : (u | 0x80000000u);
}
__device__ __forceinline__ float u2f(unsigned u) {
  unsigned v = (u & 0x80000000u) ? (u & 0x7FFFFFFFu) : ~u;
  return __uint_as_float(v);
}

__global__ __launch_bounds__(256) void attn_kernel(
    const float* __restrict__ q, const float* __restrict__ k,
    const float* __restrict__ v, const float* __restrict__ span_params,
    float* __restrict__ y)
{
  __shared__ float s[T_DIM];
  __shared__ float qs[HD];
  __shared__ float red[256];
  __shared__ unsigned hist[256];
  __shared__ unsigned scan[256];
  __shared__ int sh_b, sh_w;

  const int tid = threadIdx.x;
  const int qi = blockIdx.x;
  const int h = blockIdx.y;
  const int n = qi + 1;
  const float* kh = k + (((size_t)h * T_DIM) << 6);
  const float* vh = v + (((size_t)h * T_DIM) << 6);

  if (tid < HD) qs[tid] = q[((((size_t)h * T_DIM) + qi) << 6) + tid];
  __syncthreads();

  // scores s[j] = q . k_j / 8
  for (int j = tid; j < n; j += 256) {
    const float4* kr = (const float4*)(kh + ((size_t)j << 6));
    float acc = 0.f;
#pragma unroll
    for (int d4 = 0; d4 < 16; ++d4) {
      float4 kv4 = kr[d4];
      acc = fmaf(qs[4 * d4 + 0], kv4.x, acc);
      acc = fmaf(qs[4 * d4 + 1], kv4.y, acc);
      acc = fmaf(qs[4 * d4 + 2], kv4.z, acc);
      acc = fmaf(qs[4 * d4 + 3], kv4.w, acc);
    }
    s[j] = acc * 0.125f;
  }
  __syncthreads();

  // row max
  float lm = -INFINITY;
  for (int j = tid; j < n; j += 256) lm = fmaxf(lm, s[j]);
  red[tid] = lm; __syncthreads();
#pragma unroll
  for (int off = 128; off > 0; off >>= 1) {
    if (tid < off) red[tid] = fmaxf(red[tid], red[tid + off]);
    __syncthreads();
  }
  const float mrow = red[0];
  __syncthreads();

  // exact rank-64 threshold via radix select on order-preserving bits
  float thresh = -INFINITY;
  if (n > TOPK_K) {
    unsigned prefix = 0;
    int want = TOPK_K;
    for (int shift = 24; shift >= 0; shift -= 8) {
      hist[tid] = 0;
      __syncthreads();
      unsigned pm = (shift == 24) ? 0u : (0xFFFFFFFFu << (shift + 8));
      for (int j = tid; j < n; j += 256) {
        unsigned u = f2u(s[j]);
        if ((u & pm) == prefix)
          atomicAdd(&hist[(u >> shift) & 0xFFu], 1u);
      }
      __syncthreads();
      scan[tid] = hist[tid];
      __syncthreads();
      for (int off = 1; off < 256; off <<= 1) {
        unsigned tv = (tid + off < 256) ? scan[tid + off] : 0u;
        __syncthreads();
        scan[tid] += tv;
        __syncthreads();
      }
      unsigned ge = scan[tid];
      unsigned geN = (tid < 255) ? scan[tid + 1] : 0u;
      if (ge >= (unsigned)want && geN < (unsigned)want) {
        sh_b = tid;
        sh_w = want - (int)geN;
      }
      __syncthreads();
      prefix |= ((unsigned)sh_b) << shift;
      want = sh_w;
      __syncthreads();
    }
    thresh = u2f(prefix);
  }

  // softmax over kept entries
  float lz = 0.f;
  for (int j = tid; j < n; j += 256) {
    float sv = s[j];
    float w = (sv >= thresh) ? expf(sv - mrow) : 0.f;
    s[j] = w;
    lz += w;
  }
  red[tid] = lz; __syncthreads();
#pragma unroll
  for (int off = 128; off > 0; off >>= 1) {
    if (tid < off) red[tid] += red[tid + off];
    __syncthreads();
  }
  const float Z = red[0];
  __syncthreads();
  const float invZ = 1.f / Z;

  // span mask + renorm sum
  const float span = 2048.f * fminf(fmaxf(span_params[h], 0.f), 1.f);
  float l2 = 0.f;
  for (int j = tid; j < n; j += 256) {
    float dist = (float)(qi - j);
    float msk = fminf(fmaxf((32.f + span - dist) * (1.f / 32.f), 0.f), 1.f);
    float a = s[j] * invZ * msk;
    s[j] = a;
    l2 += a;
  }
  red[tid] = l2; __syncthreads();
#pragma unroll
  for (int off = 128; off > 0; off >>= 1) {
    if (tid < off) red[tid] += red[tid + off];
    __syncthreads();
  }
  const float S2 = red[0];
  __syncthreads();
  const float scale = 1.f / (S2 + 1e-8f);

  // PV: y[d] = scale * sum_j s[j] * v[j][d]
  const int d = tid & 63;
  const int cpart = tid >> 6;
  float p = 0.f;
  for (int j = cpart; j < n; j += 4)
    p = fmaf(s[j], vh[((size_t)j << 6) + d], p);
  red[tid] = p;
  __syncthreads();
  if (tid < 64) {
    float r = red[tid] + red[tid + 64] + red[tid + 128] + red[tid + 192];
    y[((((size_t)h * T_DIM) + qi) << 6) + tid] = r * scale;
  }
}

// ---------------- elementwise gating (head-major -> row-major) ----------------
__global__ void gate_mul_kernel(const float* __restrict__ y_att,
                                const float* __restrict__ gate,
                                float* __restrict__ yg) {
  int idx = blockIdx.x * blockDim.x + threadIdx.x;
  if (idx >= T_DIM * C_DIM) return;
  int t = idx >> 10;
  int c = idx & 1023;
  int h = c >> 6, d = c & 63;
  yg[idx] = y_att[(((size_t)(h * T_DIM + t)) << 6) + d] * gate[idx];
}

extern "C" void kernel_launch(void* const* d_in, const int* in_sizes, int n_in,
                              void* d_out, int out_size, void* d_ws, size_t ws_size,
                              hipStream_t stream) {
  (void)in_sizes; (void)n_in; (void)out_size; (void)ws_size;
  const float* x           = (const float*)d_in[0];
  const float* w_attn      = (const float*)d_in[1];
  const float* w_proj      = (const float*)d_in[2];
  const float* w_gate      = (const float*)d_in[3];
  const float* span_params = (const float*)d_in[4];
  // d_in[5] = pos : unused (reference uses arange internally)
  float* out = (float*)d_out;

  char* ws = (char*)d_ws;
  const size_t SZ = (size_t)T_DIM * C_DIM * sizeof(float); // 8 MB
  float* q     = (float*)(ws);
  float* k     = (float*)(ws + SZ);
  float* v     = (float*)(ws + 2 * SZ);
  float* gate  = (float*)(ws + 3 * SZ);
  float* y_att = (float*)(ws + 4 * SZ);
  float* yg    = q; // q dead after attention

  dim3 blk(256);
  // qkv = x @ w_attn^T, scattered head-major
  gemm_kernel<<<dim3(3 * C_DIM / BN, T_DIM / BM), blk, 0, stream>>>(
      x, w_attn, q, k, v, T_DIM, 3 * C_DIM, C_DIM, 0);
  // RoPE in place
  rope_kernel<<<(H_DIM * T_DIM * 32) / 256, blk, 0, stream>>>(q, k);
  // gate = silu(x @ w_gate^T)
  gemm_kernel<<<dim3(C_DIM / BN, T_DIM / BM), blk, 0, stream>>>(
      x, w_gate, gate, nullptr, nullptr, T_DIM, C_DIM, C_DIM, 1);
  // attention
  attn_kernel<<<dim3(T_DIM, H_DIM), blk, 0, stream>>>(q, k, v, span_params, y_att);
  // gating
  gate_mul_kernel<<<(T_DIM * C_DIM) / 256, blk, 0, stream>>>(y_att, gate, yg);
  // out = yg @ w_proj^T
  gemm_kernel<<<dim3(C_DIM / BN, T_DIM / BM), blk, 0, stream>>>(
      yg, w_proj, out, nullptr, nullptr, T_DIM, C_DIM, C_DIM, 2);
}

// Round 2
// 1634.125 us; speedup vs baseline: 2.2050x; 2.2050x over previous
//
#include <hip/hip_runtime.h>
#include <math.h>

#define T_DIM 2048
#define C_DIM 1024
#define H_DIM 16
#define HD 64
#define TOPK_K 64

// ---------------- GEMM: C = A[M][K] @ B[N][K]^T ----------------
#define BM 64
#define BN 64
#define BK 16
#define LDSP (BM + 4)

// mode 0: scatter qkv into head-major q/k/v [H][T][64]
// mode 1: silu epilogue, row-major C0[M][N]
// mode 2: plain row-major C0[M][N]
__global__ __launch_bounds__(256) void gemm_kernel(
    const float* __restrict__ A, const float* __restrict__ B,
    float* __restrict__ C0, float* __restrict__ C1, float* __restrict__ C2,
    int M, int N, int K, int mode)
{
  __shared__ float As[BK][LDSP];
  __shared__ float Bs[BK][LDSP];
  const int tid = threadIdx.x;
  const int m0 = blockIdx.y * BM, n0 = blockIdx.x * BN;
  const int tm = tid >> 4, tn = tid & 15;
  const int lr = tid >> 2, lc = (tid & 3) << 2;
  float acc[4][4] = {};
  const float* Aptr = A + (size_t)(m0 + lr) * K + lc;
  const float* Bptr = B + (size_t)(n0 + lr) * K + lc;
  for (int k0 = 0; k0 < K; k0 += BK) {
    float4 av = *(const float4*)(Aptr + k0);
    float4 bv = *(const float4*)(Bptr + k0);
    As[lc + 0][lr] = av.x; As[lc + 1][lr] = av.y;
    As[lc + 2][lr] = av.z; As[lc + 3][lr] = av.w;
    Bs[lc + 0][lr] = bv.x; Bs[lc + 1][lr] = bv.y;
    Bs[lc + 2][lr] = bv.z; Bs[lc + 3][lr] = bv.w;
    __syncthreads();
#pragma unroll
    for (int kk = 0; kk < BK; ++kk) {
      float4 a4 = *(const float4*)&As[kk][tm << 2];
      float4 b4 = *(const float4*)&Bs[kk][tn << 2];
      float a[4] = {a4.x, a4.y, a4.z, a4.w};
      float b[4] = {b4.x, b4.y, b4.z, b4.w};
#pragma unroll
      for (int i = 0; i < 4; ++i)
#pragma unroll
        for (int j = 0; j < 4; ++j)
          acc[i][j] = fmaf(a[i], b[j], acc[i][j]);
    }
    __syncthreads();
  }
  if (mode == 0) {
    const int which = n0 >> 10;          // 0=q 1=k 2=v
    const int h = (n0 & 1023) >> 6;      // head (n0 is 64-aligned)
    float* dst = (which == 0) ? C0 : (which == 1) ? C1 : C2;
#pragma unroll
    for (int i = 0; i < 4; ++i) {
      int m = m0 + (tm << 2) + i;
      float4 o = {acc[i][0], acc[i][1], acc[i][2], acc[i][3]};
      *(float4*)(dst + (((size_t)(h * T_DIM + m)) << 6) + (tn << 2)) = o;
    }
  } else if (mode == 1) {
#pragma unroll
    for (int i = 0; i < 4; ++i) {
      int m = m0 + (tm << 2) + i;
      float4 o;
      float* po = &o.x;
#pragma unroll
      for (int j = 0; j < 4; ++j) {
        float vv = acc[i][j];
        po[j] = vv / (1.f + expf(-vv));   // silu
      }
      *(float4*)(C0 + (size_t)m * N + n0 + (tn << 2)) = o;
    }
  } else {
#pragma unroll
    for (int i = 0; i < 4; ++i) {
      int m = m0 + (tm << 2) + i;
      float4 o = {acc[i][0], acc[i][1], acc[i][2], acc[i][3]};
      *(float4*)(C0 + (size_t)m * N + n0 + (tn << 2)) = o;
    }
  }
}

// ---------------- RoPE in-place on head-major q,k ----------------
__global__ void rope_kernel(float* __restrict__ q, float* __restrict__ k) {
  int idx = blockIdx.x * blockDim.x + threadIdx.x;
  if (idx >= H_DIM * T_DIM * 32) return;
  int d = idx & 31;
  int t = (idx >> 5) & (T_DIM - 1);
  int h = idx >> 16;
  size_t base = ((size_t)(h * T_DIM + t)) << 6;
  double invf = exp(-(double)d * (log(10000.0) / 32.0));
  double ang = (double)t * invf;
  double cs = cos(ang), sn = sin(ang);
  float q1 = q[base + d], q2 = q[base + d + 32];
  q[base + d]      = (float)((double)q1 * cs - (double)q2 * sn);
  q[base + d + 32] = (float)((double)q2 * cs + (double)q1 * sn);
  float k1 = k[base + d], k2 = k[base + d + 32];
  k[base + d]      = (float)((double)k1 * cs - (double)k2 * sn);
  k[base + d + 32] = (float)((double)k2 * cs + (double)k1 * sn);
}

// ---------------- attention (one wave per (head, query)) ----------------
__device__ __forceinline__ unsigned f2u(float f) {
  unsigned u = __float_as_uint(f);
  return (u & 0x80000000u) ? ~u : (u | 0x80000000u);
}
__device__ __forceinline__ float u2f(unsigned u) {
  unsigned v = (u & 0x80000000u) ? (u & 0x7FFFFFFFu) : ~u;
  return __uint_as_float(v);
}

__global__ __launch_bounds__(64) void attn_kernel(
    const float* __restrict__ q, const float* __restrict__ k,
    const float* __restrict__ v, const float* __restrict__ span_params,
    float* __restrict__ y)
{
  __shared__ float s[T_DIM];          // scores -> weights
  __shared__ unsigned hist[256];
  __shared__ int sh_b, sh_w;

  const int lane = threadIdx.x;       // 0..63
  const int qi = blockIdx.x;
  const int h = blockIdx.y;
  const int n = qi + 1;
  const float* kh = k + (((size_t)h * T_DIM) << 6);
  const float* vh = v + (((size_t)h * T_DIM) << 6);

  // q row -> registers (same row for all lanes; broadcast loads)
  float qreg[HD];
  {
    const float4* qr = (const float4*)(q + ((((size_t)h * T_DIM) + qi) << 6));
#pragma unroll
    for (int i = 0; i < 16; ++i) {
      float4 t4 = qr[i];
      qreg[4 * i + 0] = t4.x; qreg[4 * i + 1] = t4.y;
      qreg[4 * i + 2] = t4.z; qreg[4 * i + 3] = t4.w;
    }
  }

  // ---- scores + row max (lane-per-row) ----
  float lm = -INFINITY;
  for (int j = lane; j < n; j += 64) {
    const float4* kr = (const float4*)(kh + ((size_t)j << 6));
    float acc = 0.f;
#pragma unroll
    for (int d4 = 0; d4 < 16; ++d4) {
      float4 kv4 = kr[d4];
      acc = fmaf(qreg[4 * d4 + 0], kv4.x, acc);
      acc = fmaf(qreg[4 * d4 + 1], kv4.y, acc);
      acc = fmaf(qreg[4 * d4 + 2], kv4.z, acc);
      acc = fmaf(qreg[4 * d4 + 3], kv4.w, acc);
    }
    float sv = acc * 0.125f;
    s[j] = sv;
    lm = fmaxf(lm, sv);
  }
#pragma unroll
  for (int off = 32; off > 0; off >>= 1)
    lm = fmaxf(lm, __shfl_xor(lm, off, 64));
  const float mrow = lm;
  __syncthreads();

  // ---- exact rank-64 threshold: wave-synchronous radix-256 select ----
  float thresh = -INFINITY;
  if (n > TOPK_K) {
    unsigned prefix = 0;
    int want = TOPK_K;
#pragma unroll
    for (int shift = 24; shift >= 0; shift -= 8) {
      hist[lane] = 0; hist[lane + 64] = 0; hist[lane + 128] = 0; hist[lane + 192] = 0;
      __syncthreads();
      const unsigned pm = (shift == 24) ? 0u : (0xFFFFFFFFu << (shift + 8));
      for (int j = lane; j < n; j += 64) {
        unsigned u = f2u(s[j]);
        if ((u & pm) == prefix)
          atomicAdd(&hist[(u >> shift) & 255u], 1u);
      }
      __syncthreads();
      // lane covers bins 4l..4l+3
      unsigned h0 = hist[4 * lane + 0], h1 = hist[4 * lane + 1];
      unsigned h2 = hist[4 * lane + 2], h3 = hist[4 * lane + 3];
      unsigned loc = h0 + h1 + h2 + h3;
      // inclusive suffix scan of loc across lanes
      unsigned suf = loc;
#pragma unroll
      for (int off = 1; off < 64; off <<= 1) {
        unsigned t = __shfl_down(suf, off, 64);
        suf += (lane + off < 64) ? t : 0u;
      }
      unsigned sufE = suf - loc;            // count in bins > 4l+3
      unsigned S3 = sufE + h3;              // count >= bin 4l+3
      unsigned S2 = S3 + h2;
      unsigned S1 = S2 + h1;
      unsigned S0 = S1 + h0;                // count >= bin 4l
      unsigned w = (unsigned)want;
      if (S0 >= w && S1 < w) { sh_b = 4 * lane + 0; sh_w = (int)(w - S1); }
      if (S1 >= w && S2 < w) { sh_b = 4 * lane + 1; sh_w = (int)(w - S2); }
      if (S2 >= w && S3 < w) { sh_b = 4 * lane + 2; sh_w = (int)(w - S3); }
      if (S3 >= w && sufE < w) { sh_b = 4 * lane + 3; sh_w = (int)(w - sufE); }
      __syncthreads();
      prefix |= ((unsigned)sh_b) << shift;
      want = sh_w;
      __syncthreads();
    }
    thresh = u2f(prefix);
  }

  // ---- fused: topk-softmax weights + span mask + both sums ----
  const float span = 2048.f * fminf(fmaxf(span_params[h], 0.f), 1.f);
  float Zl = 0.f, Ul = 0.f;
  for (int j = lane; j < n; j += 64) {
    float sv = s[j];
    float wv = (sv >= thresh) ? __expf(sv - mrow) : 0.f;
    Zl += wv;
    float dist = (float)(qi - j);
    float msk = fminf(fmaxf((32.f + span - dist) * (1.f / 32.f), 0.f), 1.f);
    float wm = wv * msk;
    s[j] = wm;
    Ul += wm;
  }
#pragma unroll
  for (int off = 32; off > 0; off >>= 1) {
    Zl += __shfl_xor(Zl, off, 64);
    Ul += __shfl_xor(Ul, off, 64);
  }
  const float scale = 1.f / (Ul + 1e-8f * Zl);
  __syncthreads();

  // ---- PV: wave covers 4 consecutive rows x 64 dims (coalesced) ----
  // skip rows where span mask is exactly zero
  int jlo = qi - (int)(span + 32.f) - 1;
  if (jlo < 0) jlo = 0;
  jlo &= ~3;
  const int d4 = (lane & 15) << 2;    // dim base
  const int g = lane >> 4;            // row offset within group of 4
  float ax = 0.f, ay = 0.f, az = 0.f, aw = 0.f;
  for (int jb = jlo; jb < n; jb += 4) {
    int j = jb + g;
    float wv = (j < n) ? s[j] : 0.f;
    const float4 vv = *(const float4*)(vh + ((size_t)j << 6) + d4);
    ax = fmaf(wv, vv.x, ax);
    ay = fmaf(wv, vv.y, ay);
    az = fmaf(wv, vv.z, az);
    aw = fmaf(wv, vv.w, aw);
  }
#pragma unroll
  for (int off = 16; off <= 32; off <<= 1) {
    ax += __shfl_xor(ax, off, 64);
    ay += __shfl_xor(ay, off, 64);
    az += __shfl_xor(az, off, 64);
    aw += __shfl_xor(aw, off, 64);
  }
  if (g == 0) {
    float4 o = {ax * scale, ay * scale, az * scale, aw * scale};
    *(float4*)(y + ((((size_t)h * T_DIM) + qi) << 6) + d4) = o;
  }
}

// ---------------- elementwise gating (head-major -> row-major) ----------------
__global__ void gate_mul_kernel(const float* __restrict__ y_att,
                                const float* __restrict__ gate,
                                float* __restrict__ yg) {
  int idx = blockIdx.x * blockDim.x + threadIdx.x;
  if (idx >= T_DIM * C_DIM) return;
  int t = idx >> 10;
  int c = idx & 1023;
  int h = c >> 6, d = c & 63;
  yg[idx] = y_att[(((size_t)(h * T_DIM + t)) << 6) + d] * gate[idx];
}

extern "C" void kernel_launch(void* const* d_in, const int* in_sizes, int n_in,
                              void* d_out, int out_size, void* d_ws, size_t ws_size,
                              hipStream_t stream) {
  (void)in_sizes; (void)n_in; (void)out_size; (void)ws_size;
  const float* x           = (const float*)d_in[0];
  const float* w_attn      = (const float*)d_in[1];
  const float* w_proj      = (const float*)d_in[2];
  const float* w_gate      = (const float*)d_in[3];
  const float* span_params = (const float*)d_in[4];
  // d_in[5] = pos : unused (reference uses arange internally)
  float* out = (float*)d_out;

  char* ws = (char*)d_ws;
  const size_t SZ = (size_t)T_DIM * C_DIM * sizeof(float); // 8 MB
  float* q     = (float*)(ws);
  float* k     = (float*)(ws + SZ);
  float* v     = (float*)(ws + 2 * SZ);
  float* gate  = (float*)(ws + 3 * SZ);
  float* y_att = (float*)(ws + 4 * SZ);
  float* yg    = q; // q dead after attention

  // qkv = x @ w_attn^T, scattered head-major
  gemm_kernel<<<dim3(3 * C_DIM / BN, T_DIM / BM), dim3(256), 0, stream>>>(
      x, w_attn, q, k, v, T_DIM, 3 * C_DIM, C_DIM, 0);
  // RoPE in place
  rope_kernel<<<(H_DIM * T_DIM * 32) / 256, dim3(256), 0, stream>>>(q, k);
  // gate = silu(x @ w_gate^T)
  gemm_kernel<<<dim3(C_DIM / BN, T_DIM / BM), dim3(256), 0, stream>>>(
      x, w_gate, gate, nullptr, nullptr, T_DIM, C_DIM, C_DIM, 1);
  // attention: one 64-lane wave per (query, head)
  attn_kernel<<<dim3(T_DIM, H_DIM), dim3(64), 0, stream>>>(q, k, v, span_params, y_att);
  // gating
  gate_mul_kernel<<<(T_DIM * C_DIM) / 256, dim3(256), 0, stream>>>(y_att, gate, yg);
  // out = yg @ w_proj^T
  gemm_kernel<<<dim3(C_DIM / BN, T_DIM / BM), dim3(256), 0, stream>>>(
      yg, w_proj, out, nullptr, nullptr, T_DIM, C_DIM, C_DIM, 2);
}

// Round 3
// 1087.040 us; speedup vs baseline: 3.3148x; 1.5033x over previous
//
#include <hip/hip_runtime.h>
#include <math.h>

#define T_DIM 2048
#define C_DIM 1024
#define H_DIM 16
#define HD 64
#define TOPK_K 64
#define QTILE 4
#define LCAP 128

// ---------------- GEMM: C = A[M][K] @ B[N][K]^T ----------------
#define BM 64
#define BN 64
#define BK 16
#define LDSP (BM + 4)

// mode 0: scatter qkv into head-major q/k/v [H][T][64]
// mode 1: silu epilogue, row-major C0[M][N]
// mode 2: plain row-major C0[M][N]
__global__ __launch_bounds__(256) void gemm_kernel(
    const float* __restrict__ A, const float* __restrict__ B,
    float* __restrict__ C0, float* __restrict__ C1, float* __restrict__ C2,
    int M, int N, int K, int mode)
{
  __shared__ float As[BK][LDSP];
  __shared__ float Bs[BK][LDSP];
  const int tid = threadIdx.x;
  const int m0 = blockIdx.y * BM, n0 = blockIdx.x * BN;
  const int tm = tid >> 4, tn = tid & 15;
  const int lr = tid >> 2, lc = (tid & 3) << 2;
  float acc[4][4] = {};
  const float* Aptr = A + (size_t)(m0 + lr) * K + lc;
  const float* Bptr = B + (size_t)(n0 + lr) * K + lc;
  for (int k0 = 0; k0 < K; k0 += BK) {
    float4 av = *(const float4*)(Aptr + k0);
    float4 bv = *(const float4*)(Bptr + k0);
    As[lc + 0][lr] = av.x; As[lc + 1][lr] = av.y;
    As[lc + 2][lr] = av.z; As[lc + 3][lr] = av.w;
    Bs[lc + 0][lr] = bv.x; Bs[lc + 1][lr] = bv.y;
    Bs[lc + 2][lr] = bv.z; Bs[lc + 3][lr] = bv.w;
    __syncthreads();
#pragma unroll
    for (int kk = 0; kk < BK; ++kk) {
      float4 a4 = *(const float4*)&As[kk][tm << 2];
      float4 b4 = *(const float4*)&Bs[kk][tn << 2];
      float a[4] = {a4.x, a4.y, a4.z, a4.w};
      float b[4] = {b4.x, b4.y, b4.z, b4.w};
#pragma unroll
      for (int i = 0; i < 4; ++i)
#pragma unroll
        for (int j = 0; j < 4; ++j)
          acc[i][j] = fmaf(a[i], b[j], acc[i][j]);
    }
    __syncthreads();
  }
  if (mode == 0) {
    const int which = n0 >> 10;
    const int h = (n0 & 1023) >> 6;
    float* dst = (which == 0) ? C0 : (which == 1) ? C1 : C2;
#pragma unroll
    for (int i = 0; i < 4; ++i) {
      int m = m0 + (tm << 2) + i;
      float4 o = {acc[i][0], acc[i][1], acc[i][2], acc[i][3]};
      *(float4*)(dst + (((size_t)(h * T_DIM + m)) << 6) + (tn << 2)) = o;
    }
  } else if (mode == 1) {
#pragma unroll
    for (int i = 0; i < 4; ++i) {
      int m = m0 + (tm << 2) + i;
      float4 o;
      float* po = &o.x;
#pragma unroll
      for (int j = 0; j < 4; ++j) {
        float vv = acc[i][j];
        po[j] = vv / (1.f + expf(-vv));
      }
      *(float4*)(C0 + (size_t)m * N + n0 + (tn << 2)) = o;
    }
  } else {
#pragma unroll
    for (int i = 0; i < 4; ++i) {
      int m = m0 + (tm << 2) + i;
      float4 o = {acc[i][0], acc[i][1], acc[i][2], acc[i][3]};
      *(float4*)(C0 + (size_t)m * N + n0 + (tn << 2)) = o;
    }
  }
}

// ---------------- RoPE in-place on head-major q,k ----------------
__global__ void rope_kernel(float* __restrict__ q, float* __restrict__ k) {
  int idx = blockIdx.x * blockDim.x + threadIdx.x;
  if (idx >= H_DIM * T_DIM * 32) return;
  int d = idx & 31;
  int t = (idx >> 5) & (T_DIM - 1);
  int h = idx >> 16;
  size_t base = ((size_t)(h * T_DIM + t)) << 6;
  double invf = exp(-(double)d * (log(10000.0) / 32.0));
  double ang = (double)t * invf;
  double cs = cos(ang), sn = sin(ang);
  float q1 = q[base + d], q2 = q[base + d + 32];
  q[base + d]      = (float)((double)q1 * cs - (double)q2 * sn);
  q[base + d + 32] = (float)((double)q2 * cs + (double)q1 * sn);
  float k1 = k[base + d], k2 = k[base + d + 32];
  k[base + d]      = (float)((double)k1 * cs - (double)k2 * sn);
  k[base + d + 32] = (float)((double)k2 * cs + (double)k1 * sn);
}

// ---------------- attention ----------------
// Block = 256 threads = 4 waves; wave w handles query q0+w of head blockIdx.y.
// K tiles (64 rows x 64 dims) staged in LDS (XOR-swizzled), shared by 4 waves.
__device__ __forceinline__ unsigned f2u(float f) {
  unsigned u = __float_as_uint(f);
  return (u & 0x80000000u) ? ~u : (u | 0x80000000u);
}
__device__ __forceinline__ float u2f(unsigned u) {
  unsigned v = (u & 0x80000000u) ? (u & 0x7FFFFFFFu) : ~u;
  return __uint_as_float(v);
}

__global__ __launch_bounds__(256) void attn_kernel(
    const float* __restrict__ q, const float* __restrict__ k,
    const float* __restrict__ v, const float* __restrict__ span_params,
    float* __restrict__ y)
{
  __shared__ __align__(16) float kt[64][64];           // swizzled K tile
  __shared__ __align__(16) float s[QTILE][T_DIM];      // scores per query
  __shared__ __align__(16) unsigned hist[QTILE][256];
  __shared__ int listIdx[QTILE][LCAP];
  __shared__ float listW[QTILE][LCAP];
  __shared__ int sh_b[QTILE], sh_w[QTILE], sh_cnt[QTILE];

  const int tid = threadIdx.x;
  const int lane = tid & 63;
  const int w = tid >> 6;
  const int q0 = blockIdx.x * QTILE;
  const int h = blockIdx.y;
  const int qi = q0 + w;
  const int n = qi + 1;
  const float* kh = k + (((size_t)h * T_DIM) << 6);
  const float* vh = v + (((size_t)h * T_DIM) << 6);

  // q row -> registers
  float4 qreg[16];
  {
    const float4* qr = (const float4*)(q + ((((size_t)h * T_DIM) + qi) << 6));
#pragma unroll
    for (int i = 0; i < 16; ++i) qreg[i] = qr[i];
  }

  // staging mapping: thread covers rows sr+{0,16,32,48}, 16-B chunk sc
  const int sr = tid >> 4;
  const int sc = tid & 15;
  const int nmax = q0 + QTILE;
  const int ntiles = (nmax + 63) >> 6;

  float4 pf[4];
#pragma unroll
  for (int i = 0; i < 4; ++i) {
    int r = sr + (i << 4);
    pf[i] = *(const float4*)(kh + ((size_t)r << 6) + (sc << 2));
  }

  const char* kbase = (const char*)&kt[0][0] + (lane << 8);
  const int sw = (lane & 15) << 4;

  float lm = -INFINITY;
  for (int tt = 0; tt < ntiles; ++tt) {
    const int t0 = tt << 6;
    // write prefetched tile into LDS (swizzled: chunk c of row r -> col c^(r&15))
#pragma unroll
    for (int i = 0; i < 4; ++i) {
      int r = sr + (i << 4);
      *(float4*)((char*)&kt[r][0] + (((sc << 4) ^ ((r & 15) << 4)))) = pf[i];
    }
    __syncthreads();
    // prefetch next tile
    if (tt + 1 < ntiles) {
      const int t0n = t0 + 64;
#pragma unroll
      for (int i = 0; i < 4; ++i) {
        int r = sr + (i << 4);
        pf[i] = *(const float4*)(kh + ((size_t)(t0n + r) << 6) + (sc << 2));
      }
    }
    // per-wave: score for row j = t0 + lane
    const int j = t0 + lane;
    if (j < n) {
      float accv[4] = {0.f, 0.f, 0.f, 0.f};
#pragma unroll
      for (int tb = 0; tb < 4; ++tb) {
#pragma unroll
        for (int u = 0; u < 4; ++u) {
          const int t = tb * 4 + u;
          const float4 kv = *(const float4*)(kbase + (sw ^ (t << 4)));
          const float4 qv = qreg[t];
          accv[u] = fmaf(qv.x, kv.x, accv[u]);
          accv[u] = fmaf(qv.y, kv.y, accv[u]);
          accv[u] = fmaf(qv.z, kv.z, accv[u]);
          accv[u] = fmaf(qv.w, kv.w, accv[u]);
        }
      }
      float sv = (accv[0] + accv[1] + accv[2] + accv[3]) * 0.125f;
      s[w][j] = sv;
      lm = fmaxf(lm, sv);
    }
    __syncthreads();
  }

  // wave-level row max
#pragma unroll
  for (int off = 32; off > 0; off >>= 1)
    lm = fmaxf(lm, __shfl_xor(lm, off, 64));
  const float mrow = lm;

  // ---- exact rank-64 threshold: per-wave radix-256 select ----
  float thresh = -INFINITY;
  if (n > TOPK_K) {
    unsigned prefix = 0;
    int want = TOPK_K;
#pragma unroll
    for (int shift = 24; shift >= 0; shift -= 8) {
      uint4 z4 = {0u, 0u, 0u, 0u};
      *(uint4*)&hist[w][lane << 2] = z4;
      __threadfence_block();
      const unsigned pm = (shift == 24) ? 0u : (0xFFFFFFFFu << (shift + 8));
      for (int j2 = lane; j2 < n; j2 += 64) {
        unsigned u = f2u(s[w][j2]);
        if ((u & pm) == prefix)
          atomicAdd(&hist[w][(u >> shift) & 255u], 1u);
      }
      __threadfence_block();
      uint4 hv = *(const uint4*)&hist[w][lane << 2];
      unsigned loc = hv.x + hv.y + hv.z + hv.w;
      unsigned suf = loc;
#pragma unroll
      for (int off = 1; off < 64; off <<= 1) {
        unsigned t = __shfl_down(suf, off, 64);
        suf += (lane + off < 64) ? t : 0u;
      }
      unsigned sufE = suf - loc;
      unsigned S3 = sufE + hv.w;
      unsigned S2 = S3 + hv.z;
      unsigned S1 = S2 + hv.y;
      unsigned S0 = S1 + hv.x;
      unsigned wt = (unsigned)want;
      if (S0 >= wt && S1 < wt) { sh_b[w] = 4 * lane + 0; sh_w[w] = (int)(wt - S1); }
      if (S1 >= wt && S2 < wt) { sh_b[w] = 4 * lane + 1; sh_w[w] = (int)(wt - S2); }
      if (S2 >= wt && S3 < wt) { sh_b[w] = 4 * lane + 2; sh_w[w] = (int)(wt - S3); }
      if (S3 >= wt && sufE < wt) { sh_b[w] = 4 * lane + 3; sh_w[w] = (int)(wt - sufE); }
      __threadfence_block();
      prefix |= ((unsigned)sh_b[w]) << shift;
      want = sh_w[w];
    }
    thresh = u2f(prefix);
  }

  // ---- weights: topk softmax + span mask + Z/U sums + kept-list collect ----
  const float span = 2048.f * fminf(fmaxf(span_params[h], 0.f), 1.f);
  if (lane == 0) sh_cnt[w] = 0;
  __threadfence_block();
  float Zl = 0.f, Ul = 0.f;
  for (int j2 = lane; j2 < n; j2 += 64) {
    float sv = s[w][j2];
    if (sv >= thresh) {
      float wv = __expf(sv - mrow);
      Zl += wv;
      float dist = (float)(qi - j2);
      float msk = fminf(fmaxf((32.f + span - dist) * (1.f / 32.f), 0.f), 1.f);
      float wm = wv * msk;
      if (wm > 0.f) {
        Ul += wm;
        int pos = atomicAdd(&sh_cnt[w], 1);
        if (pos < LCAP) { listIdx[w][pos] = j2; listW[w][pos] = wm; }
      }
    }
  }
#pragma unroll
  for (int off = 32; off > 0; off >>= 1) {
    Zl += __shfl_xor(Zl, off, 64);
    Ul += __shfl_xor(Ul, off, 64);
  }
  const float scale = 1.f / (Ul + 1e-8f * Zl);
  __threadfence_block();
  const int cnt = min(sh_cnt[w], LCAP);

  // ---- PV over kept list: 4 rows x 16 dim-groups per iteration ----
  const int g = lane >> 4;
  const int d4 = (lane & 15) << 2;
  float4 acc4 = {0.f, 0.f, 0.f, 0.f};
  for (int e0 = 0; e0 < cnt; e0 += 4) {
    int e = e0 + g;
    float wm = 0.f;
    int idx = 0;
    if (e < cnt) { idx = listIdx[w][e]; wm = listW[w][e]; }
    const float4 vv = *(const float4*)(vh + ((size_t)idx << 6) + d4);
    acc4.x = fmaf(wm, vv.x, acc4.x);
    acc4.y = fmaf(wm, vv.y, acc4.y);
    acc4.z = fmaf(wm, vv.z, acc4.z);
    acc4.w = fmaf(wm, vv.w, acc4.w);
  }
#pragma unroll
  for (int off = 16; off <= 32; off <<= 1) {
    acc4.x += __shfl_xor(acc4.x, off, 64);
    acc4.y += __shfl_xor(acc4.y, off, 64);
    acc4.z += __shfl_xor(acc4.z, off, 64);
    acc4.w += __shfl_xor(acc4.w, off, 64);
  }
  if (g == 0) {
    float4 o = {acc4.x * scale, acc4.y * scale, acc4.z * scale, acc4.w * scale};
    *(float4*)(y + ((((size_t)h * T_DIM) + qi) << 6) + d4) = o;
  }
}

// ---------------- elementwise gating (head-major -> row-major) ----------------
__global__ void gate_mul_kernel(const float* __restrict__ y_att,
                                const float* __restrict__ gate,
                                float* __restrict__ yg) {
  int idx = blockIdx.x * blockDim.x + threadIdx.x;
  if (idx >= T_DIM * C_DIM) return;
  int t = idx >> 10;
  int c = idx & 1023;
  int h = c >> 6, d = c & 63;
  yg[idx] = y_att[(((size_t)(h * T_DIM + t)) << 6) + d] * gate[idx];
}

extern "C" void kernel_launch(void* const* d_in, const int* in_sizes, int n_in,
                              void* d_out, int out_size, void* d_ws, size_t ws_size,
                              hipStream_t stream) {
  (void)in_sizes; (void)n_in; (void)out_size; (void)ws_size;
  const float* x           = (const float*)d_in[0];
  const float* w_attn      = (const float*)d_in[1];
  const float* w_proj      = (const float*)d_in[2];
  const float* w_gate      = (const float*)d_in[3];
  const float* span_params = (const float*)d_in[4];
  float* out = (float*)d_out;

  char* ws = (char*)d_ws;
  const size_t SZ = (size_t)T_DIM * C_DIM * sizeof(float); // 8 MB
  float* q     = (float*)(ws);
  float* k     = (float*)(ws + SZ);
  float* v     = (float*)(ws + 2 * SZ);
  float* gate  = (float*)(ws + 3 * SZ);
  float* y_att = (float*)(ws + 4 * SZ);
  float* yg    = q; // q dead after attention

  gemm_kernel<<<dim3(3 * C_DIM / BN, T_DIM / BM), dim3(256), 0, stream>>>(
      x, w_attn, q, k, v, T_DIM, 3 * C_DIM, C_DIM, 0);
  rope_kernel<<<(H_DIM * T_DIM * 32) / 256, dim3(256), 0, stream>>>(q, k);
  gemm_kernel<<<dim3(C_DIM / BN, T_DIM / BM), dim3(256), 0, stream>>>(
      x, w_gate, gate, nullptr, nullptr, T_DIM, C_DIM, C_DIM, 1);
  attn_kernel<<<dim3(T_DIM / QTILE, H_DIM), dim3(256), 0, stream>>>(
      q, k, v, span_params, y_att);
  gate_mul_kernel<<<(T_DIM * C_DIM) / 256, dim3(256), 0, stream>>>(y_att, gate, yg);
  gemm_kernel<<<dim3(C_DIM / BN, T_DIM / BM), dim3(256), 0, stream>>>(
      yg, w_proj, out, nullptr, nullptr, T_DIM, C_DIM, C_DIM, 2);
}

// Round 4
// 784.029 us; speedup vs baseline: 4.5959x; 1.3865x over previous
//
#include <hip/hip_runtime.h>
#include <math.h>

#define T_DIM 2048
#define C_DIM 1024
#define H_DIM 16
#define HD 64
#define TOPK_K 64
#define QTILE 4
#define LCAP 128

typedef __attribute__((ext_vector_type(8))) __bf16 bf16x8;
typedef __attribute__((ext_vector_type(4))) float f32x4;

// ---------------- GEMM: C = A[M][K] @ B[N][K]^T ----------------
#define BM 64
#define BN 64
#define BK 16
#define LDSP (BM + 4)

__global__ __launch_bounds__(256) void gemm_kernel(
    const float* __restrict__ A, const float* __restrict__ B,
    float* __restrict__ C0, float* __restrict__ C1, float* __restrict__ C2,
    int M, int N, int K, int mode)
{
  __shared__ float As[BK][LDSP];
  __shared__ float Bs[BK][LDSP];
  const int tid = threadIdx.x;
  const int m0 = blockIdx.y * BM, n0 = blockIdx.x * BN;
  const int tm = tid >> 4, tn = tid & 15;
  const int lr = tid >> 2, lc = (tid & 3) << 2;
  float acc[4][4] = {};
  const float* Aptr = A + (size_t)(m0 + lr) * K + lc;
  const float* Bptr = B + (size_t)(n0 + lr) * K + lc;
  for (int k0 = 0; k0 < K; k0 += BK) {
    float4 av = *(const float4*)(Aptr + k0);
    float4 bv = *(const float4*)(Bptr + k0);
    As[lc + 0][lr] = av.x; As[lc + 1][lr] = av.y;
    As[lc + 2][lr] = av.z; As[lc + 3][lr] = av.w;
    Bs[lc + 0][lr] = bv.x; Bs[lc + 1][lr] = bv.y;
    Bs[lc + 2][lr] = bv.z; Bs[lc + 3][lr] = bv.w;
    __syncthreads();
#pragma unroll
    for (int kk = 0; kk < BK; ++kk) {
      float4 a4 = *(const float4*)&As[kk][tm << 2];
      float4 b4 = *(const float4*)&Bs[kk][tn << 2];
      float a[4] = {a4.x, a4.y, a4.z, a4.w};
      float b[4] = {b4.x, b4.y, b4.z, b4.w};
#pragma unroll
      for (int i = 0; i < 4; ++i)
#pragma unroll
        for (int j = 0; j < 4; ++j)
          acc[i][j] = fmaf(a[i], b[j], acc[i][j]);
    }
    __syncthreads();
  }
  if (mode == 0) {
    const int which = n0 >> 10;
    const int h = (n0 & 1023) >> 6;
    float* dst = (which == 0) ? C0 : (which == 1) ? C1 : C2;
#pragma unroll
    for (int i = 0; i < 4; ++i) {
      int m = m0 + (tm << 2) + i;
      float4 o = {acc[i][0], acc[i][1], acc[i][2], acc[i][3]};
      *(float4*)(dst + (((size_t)(h * T_DIM + m)) << 6) + (tn << 2)) = o;
    }
  } else if (mode == 1) {
#pragma unroll
    for (int i = 0; i < 4; ++i) {
      int m = m0 + (tm << 2) + i;
      float4 o;
      float* po = &o.x;
#pragma unroll
      for (int j = 0; j < 4; ++j) {
        float vv = acc[i][j];
        po[j] = vv / (1.f + expf(-vv));
      }
      *(float4*)(C0 + (size_t)m * N + n0 + (tn << 2)) = o;
    }
  } else {
#pragma unroll
    for (int i = 0; i < 4; ++i) {
      int m = m0 + (tm << 2) + i;
      float4 o = {acc[i][0], acc[i][1], acc[i][2], acc[i][3]};
      *(float4*)(C0 + (size_t)m * N + n0 + (tn << 2)) = o;
    }
  }
}

// ---------------- RoPE + bf16 hi/lo split into MFMA fragment layout, in place.
// One 64-lane wave per 16-row tile. Frag region of tile t exactly overlays its
// fp32 rows (4 KB), so the transform is block-local: loads complete (data deps)
// before stores issue. Layout per tile (4 KB):
//   [0 KB) hi kc=0 : lane(quad,n)->8 bf16 = X[t0+n][quad*8+jj]         (jj=0..7)
//   [1 KB) hi kc=1 : ...  X[t0+n][32+quad*8+jj]
//   [2 KB) lo kc=0, [3 KB) lo kc=1
__device__ __forceinline__ unsigned short bf16rn(float x) {
  unsigned u = __float_as_uint(x);
  return (unsigned short)((u + 0x7FFFu + ((u >> 16) & 1u)) >> 16);
}

__global__ __launch_bounds__(64) void prep_frag_kernel(float* __restrict__ buf) {
  const int lane = threadIdx.x;
  const int t16 = blockIdx.x, h = blockIdx.y;
  const int nr = lane & 15, quad = lane >> 4;
  const int t = (t16 << 4) + nr;
  const float* row = buf + ((size_t)(h * T_DIM + t) << 6);
  const int d0 = quad << 3;
  float4 a0 = *(const float4*)(row + d0);
  float4 a1 = *(const float4*)(row + d0 + 4);
  float4 b0 = *(const float4*)(row + 32 + d0);
  float4 b1 = *(const float4*)(row + 32 + d0 + 4);
  float x0[8] = {a0.x, a0.y, a0.z, a0.w, a1.x, a1.y, a1.z, a1.w};
  float x1[8] = {b0.x, b0.y, b0.z, b0.w, b1.x, b1.y, b1.z, b1.w};
  unsigned short h0[8], l0[8], h1[8], l1[8];
#pragma unroll
  for (int jj = 0; jj < 8; ++jj) {
    double invf = exp(-(double)(d0 + jj) * (log(10000.0) / 32.0));
    double ang = (double)t * invf;
    double cs = cos(ang), sn = sin(ang);
    float o0 = (float)((double)x0[jj] * cs - (double)x1[jj] * sn);
    float o1 = (float)((double)x1[jj] * cs + (double)x0[jj] * sn);
    unsigned short hb = bf16rn(o0);
    h0[jj] = hb;
    l0[jj] = bf16rn(o0 - __uint_as_float((unsigned)hb << 16));
    hb = bf16rn(o1);
    h1[jj] = hb;
    l1[jj] = bf16rn(o1 - __uint_as_float((unsigned)hb << 16));
  }
  char* base = (char*)buf + (((size_t)(h * 128 + t16)) << 12);
  uint4 v;
  v.x = (unsigned)h0[0] | ((unsigned)h0[1] << 16);
  v.y = (unsigned)h0[2] | ((unsigned)h0[3] << 16);
  v.z = (unsigned)h0[4] | ((unsigned)h0[5] << 16);
  v.w = (unsigned)h0[6] | ((unsigned)h0[7] << 16);
  ((uint4*)base)[lane] = v;
  v.x = (unsigned)h1[0] | ((unsigned)h1[1] << 16);
  v.y = (unsigned)h1[2] | ((unsigned)h1[3] << 16);
  v.z = (unsigned)h1[4] | ((unsigned)h1[5] << 16);
  v.w = (unsigned)h1[6] | ((unsigned)h1[7] << 16);
  ((uint4*)(base + 1024))[lane] = v;
  v.x = (unsigned)l0[0] | ((unsigned)l0[1] << 16);
  v.y = (unsigned)l0[2] | ((unsigned)l0[3] << 16);
  v.z = (unsigned)l0[4] | ((unsigned)l0[5] << 16);
  v.w = (unsigned)l0[6] | ((unsigned)l0[7] << 16);
  ((uint4*)(base + 2048))[lane] = v;
  v.x = (unsigned)l1[0] | ((unsigned)l1[1] << 16);
  v.y = (unsigned)l1[2] | ((unsigned)l1[3] << 16);
  v.z = (unsigned)l1[4] | ((unsigned)l1[5] << 16);
  v.w = (unsigned)l1[6] | ((unsigned)l1[7] << 16);
  ((uint4*)(base + 3072))[lane] = v;
}

// ---------------- attention ----------------
__device__ __forceinline__ unsigned f2u(float f) {
  unsigned u = __float_as_uint(f);
  return (u & 0x80000000u) ? ~u : (u | 0x80000000u);
}
__device__ __forceinline__ float u2f(unsigned u) {
  unsigned v = (u & 0x80000000u) ? (u & 0x7FFFFFFFu) : ~u;
  return __uint_as_float(v);
}
__device__ __forceinline__ bf16x8 ld_frag(const uint4* p) {
  uint4 u = *p;
  return __builtin_bit_cast(bf16x8, u);
}

__global__ __launch_bounds__(256) void attn_kernel(
    const float* __restrict__ qfrag, const float* __restrict__ kfrag,
    const float* __restrict__ v, const float* __restrict__ span_params,
    float* __restrict__ y)
{
  __shared__ __align__(16) float s[QTILE][T_DIM];
  __shared__ __align__(16) unsigned hist[QTILE][256];
  __shared__ int listIdx[QTILE][LCAP];
  __shared__ float listW[QTILE][LCAP];
  __shared__ int sh_b[QTILE], sh_w[QTILE], sh_cnt[QTILE];

  const int tid = threadIdx.x;
  const int lane = tid & 63;
  const int w = tid >> 6;
  const int q0 = blockIdx.x * QTILE;
  const int h = blockIdx.y;
  const int qi = q0 + w;
  const int n = qi + 1;
  const float* vh = v + (((size_t)h * T_DIM) << 6);

  // ---- scores via bf16-split MFMA ----
  // A-frags: queries of tile16 qt (16 rows incl. our 4 at rows q0&15 .. +3)
  const int qt = q0 >> 4;
  const int qsel = (q0 & 15) >> 2;   // C-quad holding our 4 query rows
  {
    const uint4* qf = (const uint4*)((const char*)qfrag + (((size_t)(h * 128 + qt)) << 12));
    bf16x8 Ah0 = ld_frag(qf + lane);
    bf16x8 Ah1 = ld_frag(qf + 64 + lane);
    bf16x8 Al0 = ld_frag(qf + 128 + lane);
    bf16x8 Al1 = ld_frag(qf + 192 + lane);
    const int tfmax = (q0 + QTILE - 1) >> 4;
    for (int tf = w; tf <= tfmax; tf += 4) {
      const uint4* kf = (const uint4*)((const char*)kfrag + (((size_t)(h * 128 + tf)) << 12));
      bf16x8 Bh0 = ld_frag(kf + lane);
      bf16x8 Bh1 = ld_frag(kf + 64 + lane);
      bf16x8 Bl0 = ld_frag(kf + 128 + lane);
      bf16x8 Bl1 = ld_frag(kf + 192 + lane);
      f32x4 acc = {0.f, 0.f, 0.f, 0.f};
      acc = __builtin_amdgcn_mfma_f32_16x16x32_bf16(Ah0, Bh0, acc, 0, 0, 0);
      acc = __builtin_amdgcn_mfma_f32_16x16x32_bf16(Ah0, Bl0, acc, 0, 0, 0);
      acc = __builtin_amdgcn_mfma_f32_16x16x32_bf16(Al0, Bh0, acc, 0, 0, 0);
      acc = __builtin_amdgcn_mfma_f32_16x16x32_bf16(Ah1, Bh1, acc, 0, 0, 0);
      acc = __builtin_amdgcn_mfma_f32_16x16x32_bf16(Ah1, Bl1, acc, 0, 0, 0);
      acc = __builtin_amdgcn_mfma_f32_16x16x32_bf16(Al1, Bh1, acc, 0, 0, 0);
      if ((lane >> 4) == qsel) {
        const int jcol = (tf << 4) + (lane & 15);
#pragma unroll
        for (int r = 0; r < 4; ++r)
          if (jcol <= q0 + r) s[r][jcol] = acc[r] * 0.125f;
      }
    }
  }
  __syncthreads();

  // ---- row max (wave w <-> query q0+w) ----
  float lm = -INFINITY;
  for (int j = lane; j < n; j += 64) lm = fmaxf(lm, s[w][j]);
#pragma unroll
  for (int off = 32; off > 0; off >>= 1)
    lm = fmaxf(lm, __shfl_xor(lm, off, 64));
  const float mrow = lm;

  // ---- exact rank-64 threshold: per-wave radix-256 select ----
  float thresh = -INFINITY;
  if (n > TOPK_K) {
    unsigned prefix = 0;
    int want = TOPK_K;
#pragma unroll
    for (int shift = 24; shift >= 0; shift -= 8) {
      uint4 z4 = {0u, 0u, 0u, 0u};
      *(uint4*)&hist[w][lane << 2] = z4;
      __threadfence_block();
      const unsigned pm = (shift == 24) ? 0u : (0xFFFFFFFFu << (shift + 8));
      for (int j2 = lane; j2 < n; j2 += 64) {
        unsigned u = f2u(s[w][j2]);
        if ((u & pm) == prefix)
          atomicAdd(&hist[w][(u >> shift) & 255u], 1u);
      }
      __threadfence_block();
      uint4 hv = *(const uint4*)&hist[w][lane << 2];
      unsigned loc = hv.x + hv.y + hv.z + hv.w;
      unsigned suf = loc;
#pragma unroll
      for (int off = 1; off < 64; off <<= 1) {
        unsigned t = __shfl_down(suf, off, 64);
        suf += (lane + off < 64) ? t : 0u;
      }
      unsigned sufE = suf - loc;
      unsigned S3 = sufE + hv.w;
      unsigned S2 = S3 + hv.z;
      unsigned S1 = S2 + hv.y;
      unsigned S0 = S1 + hv.x;
      unsigned wt = (unsigned)want;
      if (S0 >= wt && S1 < wt) { sh_b[w] = 4 * lane + 0; sh_w[w] = (int)(wt - S1); }
      if (S1 >= wt && S2 < wt) { sh_b[w] = 4 * lane + 1; sh_w[w] = (int)(wt - S2); }
      if (S2 >= wt && S3 < wt) { sh_b[w] = 4 * lane + 2; sh_w[w] = (int)(wt - S3); }
      if (S3 >= wt && sufE < wt) { sh_b[w] = 4 * lane + 3; sh_w[w] = (int)(wt - sufE); }
      __threadfence_block();
      prefix |= ((unsigned)sh_b[w]) << shift;
      want = sh_w[w];
    }
    thresh = u2f(prefix);
  }

  // ---- weights: topk softmax + span mask + Z/U sums + kept-list collect ----
  const float span = 2048.f * fminf(fmaxf(span_params[h], 0.f), 1.f);
  if (lane == 0) sh_cnt[w] = 0;
  __threadfence_block();
  float Zl = 0.f, Ul = 0.f;
  for (int j2 = lane; j2 < n; j2 += 64) {
    float sv = s[w][j2];
    if (sv >= thresh) {
      float wv = __expf(sv - mrow);
      Zl += wv;
      float dist = (float)(qi - j2);
      float msk = fminf(fmaxf((32.f + span - dist) * (1.f / 32.f), 0.f), 1.f);
      float wm = wv * msk;
      if (wm > 0.f) {
        Ul += wm;
        int pos = atomicAdd(&sh_cnt[w], 1);
        if (pos < LCAP) { listIdx[w][pos] = j2; listW[w][pos] = wm; }
      }
    }
  }
#pragma unroll
  for (int off = 32; off > 0; off >>= 1) {
    Zl += __shfl_xor(Zl, off, 64);
    Ul += __shfl_xor(Ul, off, 64);
  }
  const float scale = 1.f / (Ul + 1e-8f * Zl);
  __threadfence_block();
  const int cnt = min(sh_cnt[w], LCAP);

  // ---- PV over kept list: 4 rows x 16 dim-groups per iteration ----
  const int g = lane >> 4;
  const int d4 = (lane & 15) << 2;
  float4 acc4 = {0.f, 0.f, 0.f, 0.f};
  for (int e0 = 0; e0 < cnt; e0 += 4) {
    int e = e0 + g;
    float wm = 0.f;
    int idx = 0;
    if (e < cnt) { idx = listIdx[w][e]; wm = listW[w][e]; }
    const float4 vv = *(const float4*)(vh + ((size_t)idx << 6) + d4);
    acc4.x = fmaf(wm, vv.x, acc4.x);
    acc4.y = fmaf(wm, vv.y, acc4.y);
    acc4.z = fmaf(wm, vv.z, acc4.z);
    acc4.w = fmaf(wm, vv.w, acc4.w);
  }
#pragma unroll
  for (int off = 16; off <= 32; off <<= 1) {
    acc4.x += __shfl_xor(acc4.x, off, 64);
    acc4.y += __shfl_xor(acc4.y, off, 64);
    acc4.z += __shfl_xor(acc4.z, off, 64);
    acc4.w += __shfl_xor(acc4.w, off, 64);
  }
  if (g == 0) {
    float4 o = {acc4.x * scale, acc4.y * scale, acc4.z * scale, acc4.w * scale};
    *(float4*)(y + ((((size_t)h * T_DIM) + qi) << 6) + d4) = o;
  }
}

// ---------------- elementwise gating (head-major -> row-major) ----------------
__global__ void gate_mul_kernel(const float* __restrict__ y_att,
                                const float* __restrict__ gate,
                                float* __restrict__ yg) {
  int idx = blockIdx.x * blockDim.x + threadIdx.x;
  if (idx >= T_DIM * C_DIM) return;
  int t = idx >> 10;
  int c = idx & 1023;
  int h = c >> 6, d = c & 63;
  yg[idx] = y_att[(((size_t)(h * T_DIM + t)) << 6) + d] * gate[idx];
}

extern "C" void kernel_launch(void* const* d_in, const int* in_sizes, int n_in,
                              void* d_out, int out_size, void* d_ws, size_t ws_size,
                              hipStream_t stream) {
  (void)in_sizes; (void)n_in; (void)out_size; (void)ws_size;
  const float* x           = (const float*)d_in[0];
  const float* w_attn      = (const float*)d_in[1];
  const float* w_proj      = (const float*)d_in[2];
  const float* w_gate      = (const float*)d_in[3];
  const float* span_params = (const float*)d_in[4];
  float* out = (float*)d_out;

  char* ws = (char*)d_ws;
  const size_t SZ = (size_t)T_DIM * C_DIM * sizeof(float); // 8 MB
  float* q     = (float*)(ws);
  float* k     = (float*)(ws + SZ);
  float* v     = (float*)(ws + 2 * SZ);
  float* gate  = (float*)(ws + 3 * SZ);
  float* y_att = (float*)(ws + 4 * SZ);
  float* yg    = q; // q region dead (frags consumed) after attention

  // qkv = x @ w_attn^T, scattered head-major fp32
  gemm_kernel<<<dim3(3 * C_DIM / BN, T_DIM / BM), dim3(256), 0, stream>>>(
      x, w_attn, q, k, v, T_DIM, 3 * C_DIM, C_DIM, 0);
  // RoPE + bf16 hi/lo split -> MFMA fragment layout, in place on q and k
  prep_frag_kernel<<<dim3(T_DIM / 16, H_DIM), dim3(64), 0, stream>>>(q);
  prep_frag_kernel<<<dim3(T_DIM / 16, H_DIM), dim3(64), 0, stream>>>(k);
  // gate = silu(x @ w_gate^T)
  gemm_kernel<<<dim3(C_DIM / BN, T_DIM / BM), dim3(256), 0, stream>>>(
      x, w_gate, gate, nullptr, nullptr, T_DIM, C_DIM, C_DIM, 1);
  // attention
  attn_kernel<<<dim3(T_DIM / QTILE, H_DIM), dim3(256), 0, stream>>>(
      q, k, v, span_params, y_att);
  // gating
  gate_mul_kernel<<<(T_DIM * C_DIM) / 256, dim3(256), 0, stream>>>(y_att, gate, yg);
  // out = yg @ w_proj^T
  gemm_kernel<<<dim3(C_DIM / BN, T_DIM / BM), dim3(256), 0, stream>>>(
      yg, w_proj, out, nullptr, nullptr, T_DIM, C_DIM, C_DIM, 2);
}

// Round 5
// 504.712 us; speedup vs baseline: 7.1393x; 1.5534x over previous
//
#include <hip/hip_runtime.h>
#include <math.h>

#define T_DIM 2048
#define C_DIM 1024
#define H_DIM 16
#define HD 64
#define TOPK_K 64
#define QTILE 4
#define LCAP 128

typedef __attribute__((ext_vector_type(8))) __bf16 bf16x8;
typedef __attribute__((ext_vector_type(4))) float f32x4;

__device__ __forceinline__ unsigned short bf16rn(float x) {
  unsigned u = __float_as_uint(x);
  return (unsigned short)((u + 0x7FFFu + ((u >> 16) & 1u)) >> 16);
}

// ---------------- fp32 -> frag-global bf16 hi/lo converter ----------------
// X [R][1024] row-major. Layout: elem((r,k)) = ((t16*32+kc)*64 + lane)*8 + jj
// with t16=r>>4, kc=k>>5, lane=(((k>>3)&3)<<4)|(r&15), jj=k&7.
// Works for both A-operand (rows=M) and B-operand (rows=N) of C=A@B^T.
__global__ __launch_bounds__(256) void convert_frag_kernel(
    const float* __restrict__ X, unsigned short* __restrict__ Xh,
    unsigned short* __restrict__ Xl)
{
  const int tid = blockIdx.x * 256 + threadIdx.x;
  const int k8 = tid & 127, r = tid >> 7;
  const float* src = X + ((size_t)r << 10) + (k8 << 3);
  float4 a = *(const float4*)src;
  float4 b = *(const float4*)(src + 4);
  float xs[8] = {a.x, a.y, a.z, a.w, b.x, b.y, b.z, b.w};
  unsigned hi[8], lo[8];
#pragma unroll
  for (int jj = 0; jj < 8; ++jj) {
    unsigned short hb = bf16rn(xs[jj]);
    hi[jj] = hb;
    lo[jj] = bf16rn(xs[jj] - __uint_as_float((unsigned)hb << 16));
  }
  const int t16 = r >> 4, rr = r & 15, kc = k8 >> 2, kq = k8 & 3;
  const size_t elem = (((size_t)(t16 * 32 + kc)) * 64 + ((kq << 4) | rr)) * 8;
  uint4 vh, vl;
  vh.x = hi[0] | (hi[1] << 16); vh.y = hi[2] | (hi[3] << 16);
  vh.z = hi[4] | (hi[5] << 16); vh.w = hi[6] | (hi[7] << 16);
  vl.x = lo[0] | (lo[1] << 16); vl.y = lo[2] | (lo[3] << 16);
  vl.z = lo[4] | (lo[5] << 16); vl.w = lo[6] | (lo[7] << 16);
  *(uint4*)(Xh + elem) = vh;
  *(uint4*)(Xl + elem) = vl;
}

// ---------------- split-bf16 MFMA GEMM: C = A[M][1024] @ B[N][1024]^T ------
// 128x128 tile, 4 waves, BK=32. Operands in frag-global hi/lo layout.
// mode 0: scatter to head-major fp32 q/k/v; mode 1: silu->C0 row-major;
// mode 2: plain C0 row-major.
__device__ __forceinline__ void gld_lds16(const unsigned short* g, unsigned short* l) {
  __builtin_amdgcn_global_load_lds(
      (const __attribute__((address_space(1))) unsigned int*)g,
      (__attribute__((address_space(3))) unsigned int*)l, 16, 0, 0);
}

__global__ __launch_bounds__(256, 2) void mgemm_kernel(
    const unsigned short* __restrict__ Ah, const unsigned short* __restrict__ Al,
    const unsigned short* __restrict__ Bh, const unsigned short* __restrict__ Bl,
    float* __restrict__ C0, float* __restrict__ C1, float* __restrict__ C2,
    int N, int mode)
{
  __shared__ __align__(16) unsigned short As[2 * 8 * 512];  // [hl][t][lane*8+jj]
  __shared__ __align__(16) unsigned short Bs[2 * 8 * 512];
  const int tid = threadIdx.x, lane = tid & 63, w = tid >> 6;
  const int mt0 = blockIdx.y << 3;   // A tile16 base
  const int nt0 = blockIdx.x << 3;   // B tile16 base

  f32x4 acc[4][4];
#pragma unroll
  for (int i = 0; i < 4; ++i)
#pragma unroll
    for (int j = 0; j < 4; ++j)
      acc[i][j] = (f32x4){0.f, 0.f, 0.f, 0.f};

  const int rA = (w >> 1) << 2, rB = (w & 1) << 2;

  for (int kc = 0; kc < 32; ++kc) {
    // stage: 32 one-wave async copies, 8 per wave (gi = w*8+li)
#pragma unroll
    for (int li = 0; li < 8; ++li) {
      const int gi = (w << 3) | li;
      const int t = gi & 7, hl = (gi >> 3) & 1, mat = gi >> 4;
      const unsigned short* gbase = mat ? (hl ? Bl : Bh) : (hl ? Al : Ah);
      const int tg = (mat ? nt0 : mt0) + t;
      const unsigned short* g = gbase + (((size_t)(tg * 32 + kc) << 6) + lane) * 8;
      unsigned short* l = (mat ? Bs : As) + hl * 4096 + t * 512;
      gld_lds16(g, l);
    }
    __syncthreads();
    bf16x8 ah[4], al[4], bh[4], bl[4];
#pragma unroll
    for (int i = 0; i < 4; ++i) {
      ah[i] = *(const bf16x8*)&As[(rA + i) * 512 + lane * 8];
      al[i] = *(const bf16x8*)&As[4096 + (rA + i) * 512 + lane * 8];
      bh[i] = *(const bf16x8*)&Bs[(rB + i) * 512 + lane * 8];
      bl[i] = *(const bf16x8*)&Bs[4096 + (rB + i) * 512 + lane * 8];
    }
#pragma unroll
    for (int i = 0; i < 4; ++i)
#pragma unroll
      for (int j = 0; j < 4; ++j) {
        acc[i][j] = __builtin_amdgcn_mfma_f32_16x16x32_bf16(ah[i], bh[j], acc[i][j], 0, 0, 0);
        acc[i][j] = __builtin_amdgcn_mfma_f32_16x16x32_bf16(ah[i], bl[j], acc[i][j], 0, 0, 0);
        acc[i][j] = __builtin_amdgcn_mfma_f32_16x16x32_bf16(al[i], bh[j], acc[i][j], 0, 0, 0);
      }
    __syncthreads();
  }

  // epilogue. C frag mapping: col=lane&15, row=quad*4+reg.
  const int col = lane & 15, quad = lane >> 4;
  const int mbase = (blockIdx.y << 7) + ((w >> 1) << 6);
  const int nbase = (blockIdx.x << 7) + ((w & 1) << 6);
  if (mode == 0) {
    const int which = nbase >> 10;
    const int h = (nbase & 1023) >> 6;   // 64-wide quadrant = exactly one head
    float* dst = (which == 0) ? C0 : (which == 1) ? C1 : C2;
    float* base = dst + (((size_t)h * T_DIM) << 6);
#pragma unroll
    for (int i = 0; i < 4; ++i)
#pragma unroll
      for (int j = 0; j < 4; ++j)
#pragma unroll
        for (int reg = 0; reg < 4; ++reg) {
          const int m = mbase + i * 16 + quad * 4 + reg;
          base[((size_t)m << 6) + j * 16 + col] = acc[i][j][reg];
        }
  } else if (mode == 1) {
#pragma unroll
    for (int i = 0; i < 4; ++i)
#pragma unroll
      for (int j = 0; j < 4; ++j)
#pragma unroll
        for (int reg = 0; reg < 4; ++reg) {
          const int m = mbase + i * 16 + quad * 4 + reg;
          float vv = acc[i][j][reg];
          C0[(size_t)m * N + nbase + j * 16 + col] = vv / (1.f + expf(-vv));
        }
  } else {
#pragma unroll
    for (int i = 0; i < 4; ++i)
#pragma unroll
      for (int j = 0; j < 4; ++j)
#pragma unroll
        for (int reg = 0; reg < 4; ++reg) {
          const int m = mbase + i * 16 + quad * 4 + reg;
          C0[(size_t)m * N + nbase + j * 16 + col] = acc[i][j][reg];
        }
  }
}

// ---------------- RoPE + bf16 hi/lo split into attention frag layout --------
__global__ __launch_bounds__(64) void prep_frag_kernel(float* __restrict__ buf) {
  const int lane = threadIdx.x;
  const int t16 = blockIdx.x, h = blockIdx.y;
  const int nr = lane & 15, quad = lane >> 4;
  const int t = (t16 << 4) + nr;
  const float* row = buf + ((size_t)(h * T_DIM + t) << 6);
  const int d0 = quad << 3;
  float4 a0 = *(const float4*)(row + d0);
  float4 a1 = *(const float4*)(row + d0 + 4);
  float4 b0 = *(const float4*)(row + 32 + d0);
  float4 b1 = *(const float4*)(row + 32 + d0 + 4);
  float x0[8] = {a0.x, a0.y, a0.z, a0.w, a1.x, a1.y, a1.z, a1.w};
  float x1[8] = {b0.x, b0.y, b0.z, b0.w, b1.x, b1.y, b1.z, b1.w};
  unsigned short h0[8], l0[8], h1[8], l1[8];
#pragma unroll
  for (int jj = 0; jj < 8; ++jj) {
    double invf = exp(-(double)(d0 + jj) * (log(10000.0) / 32.0));
    double ang = (double)t * invf;
    double cs = cos(ang), sn = sin(ang);
    float o0 = (float)((double)x0[jj] * cs - (double)x1[jj] * sn);
    float o1 = (float)((double)x1[jj] * cs + (double)x0[jj] * sn);
    unsigned short hb = bf16rn(o0);
    h0[jj] = hb;
    l0[jj] = bf16rn(o0 - __uint_as_float((unsigned)hb << 16));
    hb = bf16rn(o1);
    h1[jj] = hb;
    l1[jj] = bf16rn(o1 - __uint_as_float((unsigned)hb << 16));
  }
  char* base = (char*)buf + (((size_t)(h * 128 + t16)) << 12);
  uint4 v;
  v.x = (unsigned)h0[0] | ((unsigned)h0[1] << 16);
  v.y = (unsigned)h0[2] | ((unsigned)h0[3] << 16);
  v.z = (unsigned)h0[4] | ((unsigned)h0[5] << 16);
  v.w = (unsigned)h0[6] | ((unsigned)h0[7] << 16);
  ((uint4*)base)[lane] = v;
  v.x = (unsigned)h1[0] | ((unsigned)h1[1] << 16);
  v.y = (unsigned)h1[2] | ((unsigned)h1[3] << 16);
  v.z = (unsigned)h1[4] | ((unsigned)h1[5] << 16);
  v.w = (unsigned)h1[6] | ((unsigned)h1[7] << 16);
  ((uint4*)(base + 1024))[lane] = v;
  v.x = (unsigned)l0[0] | ((unsigned)l0[1] << 16);
  v.y = (unsigned)l0[2] | ((unsigned)l0[3] << 16);
  v.z = (unsigned)l0[4] | ((unsigned)l0[5] << 16);
  v.w = (unsigned)l0[6] | ((unsigned)l0[7] << 16);
  ((uint4*)(base + 2048))[lane] = v;
  v.x = (unsigned)l1[0] | ((unsigned)l1[1] << 16);
  v.y = (unsigned)l1[2] | ((unsigned)l1[3] << 16);
  v.z = (unsigned)l1[4] | ((unsigned)l1[5] << 16);
  v.w = (unsigned)l1[6] | ((unsigned)l1[7] << 16);
  ((uint4*)(base + 3072))[lane] = v;
}

// ---------------- attention ----------------
__device__ __forceinline__ unsigned f2u(float f) {
  unsigned u = __float_as_uint(f);
  return (u & 0x80000000u) ? ~u : (u | 0x80000000u);
}
__device__ __forceinline__ float u2f(unsigned u) {
  unsigned v = (u & 0x80000000u) ? (u & 0x7FFFFFFFu) : ~u;
  return __uint_as_float(v);
}
__device__ __forceinline__ bf16x8 ld_frag(const uint4* p) {
  uint4 u = *p;
  return __builtin_bit_cast(bf16x8, u);
}

__global__ __launch_bounds__(256) void attn_kernel(
    const float* __restrict__ qfrag, const float* __restrict__ kfrag,
    const float* __restrict__ v, const float* __restrict__ span_params,
    float* __restrict__ y)
{
  __shared__ __align__(16) float s[QTILE][T_DIM];
  __shared__ __align__(16) unsigned hist[QTILE][256];
  __shared__ int listIdx[QTILE][LCAP];
  __shared__ float listW[QTILE][LCAP];
  __shared__ int sh_b[QTILE], sh_w[QTILE], sh_cnt[QTILE];

  const int tid = threadIdx.x;
  const int lane = tid & 63;
  const int w = tid >> 6;
  const int q0 = blockIdx.x * QTILE;
  const int h = blockIdx.y;
  const int qi = q0 + w;
  const int n = qi + 1;
  const float* vh = v + (((size_t)h * T_DIM) << 6);

  // ---- scores via bf16-split MFMA ----
  const int qt = q0 >> 4;
  const int qsel = (q0 & 15) >> 2;
  {
    const uint4* qf = (const uint4*)((const char*)qfrag + (((size_t)(h * 128 + qt)) << 12));
    bf16x8 Ah0 = ld_frag(qf + lane);
    bf16x8 Ah1 = ld_frag(qf + 64 + lane);
    bf16x8 Al0 = ld_frag(qf + 128 + lane);
    bf16x8 Al1 = ld_frag(qf + 192 + lane);
    const int tfmax = (q0 + QTILE - 1) >> 4;
    for (int tf = w; tf <= tfmax; tf += 4) {
      const uint4* kf = (const uint4*)((const char*)kfrag + (((size_t)(h * 128 + tf)) << 12));
      bf16x8 Bh0 = ld_frag(kf + lane);
      bf16x8 Bh1 = ld_frag(kf + 64 + lane);
      bf16x8 Bl0 = ld_frag(kf + 128 + lane);
      bf16x8 Bl1 = ld_frag(kf + 192 + lane);
      f32x4 acc = {0.f, 0.f, 0.f, 0.f};
      acc = __builtin_amdgcn_mfma_f32_16x16x32_bf16(Ah0, Bh0, acc, 0, 0, 0);
      acc = __builtin_amdgcn_mfma_f32_16x16x32_bf16(Ah0, Bl0, acc, 0, 0, 0);
      acc = __builtin_amdgcn_mfma_f32_16x16x32_bf16(Al0, Bh0, acc, 0, 0, 0);
      acc = __builtin_amdgcn_mfma_f32_16x16x32_bf16(Ah1, Bh1, acc, 0, 0, 0);
      acc = __builtin_amdgcn_mfma_f32_16x16x32_bf16(Ah1, Bl1, acc, 0, 0, 0);
      acc = __builtin_amdgcn_mfma_f32_16x16x32_bf16(Al1, Bh1, acc, 0, 0, 0);
      if ((lane >> 4) == qsel) {
        const int jcol = (tf << 4) + (lane & 15);
#pragma unroll
        for (int r = 0; r < 4; ++r)
          if (jcol <= q0 + r) s[r][jcol] = acc[r] * 0.125f;
      }
    }
  }
  __syncthreads();

  // ---- row max ----
  float lm = -INFINITY;
  for (int j = lane; j < n; j += 64) lm = fmaxf(lm, s[w][j]);
#pragma unroll
  for (int off = 32; off > 0; off >>= 1)
    lm = fmaxf(lm, __shfl_xor(lm, off, 64));
  const float mrow = lm;

  // ---- exact rank-64 threshold: per-wave radix-256 select ----
  float thresh = -INFINITY;
  if (n > TOPK_K) {
    unsigned prefix = 0;
    int want = TOPK_K;
#pragma unroll
    for (int shift = 24; shift >= 0; shift -= 8) {
      uint4 z4 = {0u, 0u, 0u, 0u};
      *(uint4*)&hist[w][lane << 2] = z4;
      __threadfence_block();
      const unsigned pm = (shift == 24) ? 0u : (0xFFFFFFFFu << (shift + 8));
      for (int j2 = lane; j2 < n; j2 += 64) {
        unsigned u = f2u(s[w][j2]);
        if ((u & pm) == prefix)
          atomicAdd(&hist[w][(u >> shift) & 255u], 1u);
      }
      __threadfence_block();
      uint4 hv = *(const uint4*)&hist[w][lane << 2];
      unsigned loc = hv.x + hv.y + hv.z + hv.w;
      unsigned suf = loc;
#pragma unroll
      for (int off = 1; off < 64; off <<= 1) {
        unsigned t = __shfl_down(suf, off, 64);
        suf += (lane + off < 64) ? t : 0u;
      }
      unsigned sufE = suf - loc;
      unsigned S3 = sufE + hv.w;
      unsigned S2 = S3 + hv.z;
      unsigned S1 = S2 + hv.y;
      unsigned S0 = S1 + hv.x;
      unsigned wt = (unsigned)want;
      if (S0 >= wt && S1 < wt) { sh_b[w] = 4 * lane + 0; sh_w[w] = (int)(wt - S1); }
      if (S1 >= wt && S2 < wt) { sh_b[w] = 4 * lane + 1; sh_w[w] = (int)(wt - S2); }
      if (S2 >= wt && S3 < wt) { sh_b[w] = 4 * lane + 2; sh_w[w] = (int)(wt - S3); }
      if (S3 >= wt && sufE < wt) { sh_b[w] = 4 * lane + 3; sh_w[w] = (int)(wt - sufE); }
      __threadfence_block();
      prefix |= ((unsigned)sh_b[w]) << shift;
      want = sh_w[w];
    }
    thresh = u2f(prefix);
  }

  // ---- weights: topk softmax + span mask + Z/U sums + kept-list collect ----
  const float span = 2048.f * fminf(fmaxf(span_params[h], 0.f), 1.f);
  if (lane == 0) sh_cnt[w] = 0;
  __threadfence_block();
  float Zl = 0.f, Ul = 0.f;
  for (int j2 = lane; j2 < n; j2 += 64) {
    float sv = s[w][j2];
    if (sv >= thresh) {
      float wv = __expf(sv - mrow);
      Zl += wv;
      float dist = (float)(qi - j2);
      float msk = fminf(fmaxf((32.f + span - dist) * (1.f / 32.f), 0.f), 1.f);
      float wm = wv * msk;
      if (wm > 0.f) {
        Ul += wm;
        int pos = atomicAdd(&sh_cnt[w], 1);
        if (pos < LCAP) { listIdx[w][pos] = j2; listW[w][pos] = wm; }
      }
    }
  }
#pragma unroll
  for (int off = 32; off > 0; off >>= 1) {
    Zl += __shfl_xor(Zl, off, 64);
    Ul += __shfl_xor(Ul, off, 64);
  }
  const float scale = 1.f / (Ul + 1e-8f * Zl);
  __threadfence_block();
  const int cnt = min(sh_cnt[w], LCAP);

  // ---- PV over kept list ----
  const int g = lane >> 4;
  const int d4 = (lane & 15) << 2;
  float4 acc4 = {0.f, 0.f, 0.f, 0.f};
  for (int e0 = 0; e0 < cnt; e0 += 4) {
    int e = e0 + g;
    float wm = 0.f;
    int idx = 0;
    if (e < cnt) { idx = listIdx[w][e]; wm = listW[w][e]; }
    const float4 vv = *(const float4*)(vh + ((size_t)idx << 6) + d4);
    acc4.x = fmaf(wm, vv.x, acc4.x);
    acc4.y = fmaf(wm, vv.y, acc4.y);
    acc4.z = fmaf(wm, vv.z, acc4.z);
    acc4.w = fmaf(wm, vv.w, acc4.w);
  }
#pragma unroll
  for (int off = 16; off <= 32; off <<= 1) {
    acc4.x += __shfl_xor(acc4.x, off, 64);
    acc4.y += __shfl_xor(acc4.y, off, 64);
    acc4.z += __shfl_xor(acc4.z, off, 64);
    acc4.w += __shfl_xor(acc4.w, off, 64);
  }
  if (g == 0) {
    float4 o = {acc4.x * scale, acc4.y * scale, acc4.z * scale, acc4.w * scale};
    *(float4*)(y + ((((size_t)h * T_DIM) + qi) << 6) + d4) = o;
  }
}

// -------- gating: y_att (head-major) * gate -> ygf frag-global hi/lo --------
__global__ __launch_bounds__(256) void gate_mul_frag_kernel(
    const float* __restrict__ y_att, const float* __restrict__ gate,
    unsigned short* __restrict__ Yh, unsigned short* __restrict__ Yl)
{
  const int tid = blockIdx.x * 256 + threadIdx.x;
  const int k8 = tid & 127, r = tid >> 7;
  const int c0 = k8 << 3;
  const int h = c0 >> 6, d0 = c0 & 63;
  const float* ya = y_att + ((size_t)(h * T_DIM + r) << 6) + d0;
  const float* ga = gate + ((size_t)r << 10) + c0;
  float4 y0 = *(const float4*)ya;
  float4 y1 = *(const float4*)(ya + 4);
  float4 g0 = *(const float4*)ga;
  float4 g1 = *(const float4*)(ga + 4);
  float p[8] = {y0.x * g0.x, y0.y * g0.y, y0.z * g0.z, y0.w * g0.w,
                y1.x * g1.x, y1.y * g1.y, y1.z * g1.z, y1.w * g1.w};
  unsigned hi[8], lo[8];
#pragma unroll
  for (int jj = 0; jj < 8; ++jj) {
    unsigned short hb = bf16rn(p[jj]);
    hi[jj] = hb;
    lo[jj] = bf16rn(p[jj] - __uint_as_float((unsigned)hb << 16));
  }
  const int t16 = r >> 4, rr = r & 15, kc = k8 >> 2, kq = k8 & 3;
  const size_t elem = (((size_t)(t16 * 32 + kc)) * 64 + ((kq << 4) | rr)) * 8;
  uint4 vh, vl;
  vh.x = hi[0] | (hi[1] << 16); vh.y = hi[2] | (hi[3] << 16);
  vh.z = hi[4] | (hi[5] << 16); vh.w = hi[6] | (hi[7] << 16);
  vl.x = lo[0] | (lo[1] << 16); vl.y = lo[2] | (lo[3] << 16);
  vl.z = lo[4] | (lo[5] << 16); vl.w = lo[6] | (lo[7] << 16);
  *(uint4*)(Yh + elem) = vh;
  *(uint4*)(Yl + elem) = vl;
}

extern "C" void kernel_launch(void* const* d_in, const int* in_sizes, int n_in,
                              void* d_out, int out_size, void* d_ws, size_t ws_size,
                              hipStream_t stream) {
  (void)in_sizes; (void)n_in; (void)out_size; (void)ws_size;
  const float* x           = (const float*)d_in[0];
  const float* w_attn      = (const float*)d_in[1];
  const float* w_proj      = (const float*)d_in[2];
  const float* w_gate      = (const float*)d_in[3];
  const float* span_params = (const float*)d_in[4];
  float* out = (float*)d_out;

  char* ws = (char*)d_ws;
  const size_t MB = 1024 * 1024;
  float* q     = (float*)(ws);            // 8 MB
  float* k     = (float*)(ws + 8 * MB);   // 8 MB
  float* v     = (float*)(ws + 16 * MB);  // 8 MB
  float* gate  = (float*)(ws + 24 * MB);  // 8 MB
  float* y_att = (float*)(ws + 32 * MB);  // 8 MB
  unsigned short* xf_h  = (unsigned short*)(ws + 40 * MB);  // 4 MB
  unsigned short* xf_l  = (unsigned short*)(ws + 44 * MB);  // 4 MB
  unsigned short* wfa_h = (unsigned short*)(ws + 48 * MB);  // 6 MB
  unsigned short* wfa_l = (unsigned short*)(ws + 54 * MB);  // 6 MB
  unsigned short* wfg_h = (unsigned short*)(ws + 60 * MB);  // 2 MB
  unsigned short* wfg_l = (unsigned short*)(ws + 62 * MB);  // 2 MB
  unsigned short* wfp_h = (unsigned short*)(ws + 64 * MB);  // 2 MB
  unsigned short* wfp_l = (unsigned short*)(ws + 66 * MB);  // 2 MB
  unsigned short* ygf_h = (unsigned short*)(ws + 68 * MB);  // 4 MB
  unsigned short* ygf_l = (unsigned short*)(ws + 72 * MB);  // 4 MB

  // converts (K=1024 fixed; grid = R/2)
  convert_frag_kernel<<<T_DIM / 2, 256, 0, stream>>>(x, xf_h, xf_l);
  convert_frag_kernel<<<3 * C_DIM / 2, 256, 0, stream>>>(w_attn, wfa_h, wfa_l);
  convert_frag_kernel<<<C_DIM / 2, 256, 0, stream>>>(w_gate, wfg_h, wfg_l);
  convert_frag_kernel<<<C_DIM / 2, 256, 0, stream>>>(w_proj, wfp_h, wfp_l);

  // qkv = x @ w_attn^T -> head-major fp32 q/k/v
  mgemm_kernel<<<dim3(3 * C_DIM / 128, T_DIM / 128), 256, 0, stream>>>(
      xf_h, xf_l, wfa_h, wfa_l, q, k, v, 3 * C_DIM, 0);
  // RoPE + split -> attention frag layout, in place
  prep_frag_kernel<<<dim3(T_DIM / 16, H_DIM), 64, 0, stream>>>(q);
  prep_frag_kernel<<<dim3(T_DIM / 16, H_DIM), 64, 0, stream>>>(k);
  // gate = silu(x @ w_gate^T)
  mgemm_kernel<<<dim3(C_DIM / 128, T_DIM / 128), 256, 0, stream>>>(
      xf_h, xf_l, wfg_h, wfg_l, gate, nullptr, nullptr, C_DIM, 1);
  // attention
  attn_kernel<<<dim3(T_DIM / QTILE, H_DIM), 256, 0, stream>>>(
      q, k, v, span_params, y_att);
  // gating -> frag-global hi/lo
  gate_mul_frag_kernel<<<T_DIM / 2, 256, 0, stream>>>(y_att, gate, ygf_h, ygf_l);
  // out = yg @ w_proj^T
  mgemm_kernel<<<dim3(C_DIM / 128, T_DIM / 128), 256, 0, stream>>>(
      ygf_h, ygf_l, wfp_h, wfp_l, out, nullptr, nullptr, C_DIM, 2);
}

// Round 6
// 458.612 us; speedup vs baseline: 7.8570x; 1.1005x over previous
//
#include <hip/hip_runtime.h>
#include <math.h>

#define T_DIM 2048
#define C_DIM 1024
#define H_DIM 16
#define HD 64
#define TOPK_K 64
#define QTILE 4
#define LCAP 128

typedef __attribute__((ext_vector_type(8))) __bf16 bf16x8;
typedef __attribute__((ext_vector_type(4))) float f32x4;

__device__ __forceinline__ unsigned short bf16rn(float x) {
  unsigned u = __float_as_uint(x);
  return (unsigned short)((u + 0x7FFFu + ((u >> 16) & 1u)) >> 16);
}

// ---------------- fp32 -> frag-global bf16 hi/lo converter ----------------
__global__ __launch_bounds__(256) void convert_frag_kernel(
    const float* __restrict__ X, unsigned short* __restrict__ Xh,
    unsigned short* __restrict__ Xl)
{
  const int tid = blockIdx.x * 256 + threadIdx.x;
  const int k8 = tid & 127, r = tid >> 7;
  const float* src = X + ((size_t)r << 10) + (k8 << 3);
  float4 a = *(const float4*)src;
  float4 b = *(const float4*)(src + 4);
  float xs[8] = {a.x, a.y, a.z, a.w, b.x, b.y, b.z, b.w};
  unsigned hi[8], lo[8];
#pragma unroll
  for (int jj = 0; jj < 8; ++jj) {
    unsigned short hb = bf16rn(xs[jj]);
    hi[jj] = hb;
    lo[jj] = bf16rn(xs[jj] - __uint_as_float((unsigned)hb << 16));
  }
  const int t16 = r >> 4, rr = r & 15, kc = k8 >> 2, kq = k8 & 3;
  const size_t elem = (((size_t)(t16 * 32 + kc)) * 64 + ((kq << 4) | rr)) * 8;
  uint4 vh, vl;
  vh.x = hi[0] | (hi[1] << 16); vh.y = hi[2] | (hi[3] << 16);
  vh.z = hi[4] | (hi[5] << 16); vh.w = hi[6] | (hi[7] << 16);
  vl.x = lo[0] | (lo[1] << 16); vl.y = lo[2] | (lo[3] << 16);
  vl.z = lo[4] | (lo[5] << 16); vl.w = lo[6] | (lo[7] << 16);
  *(uint4*)(Xh + elem) = vh;
  *(uint4*)(Xl + elem) = vl;
}

// ---------------- split-bf16 MFMA GEMM: C = A[M][1024] @ B[N][1024]^T ------
__device__ __forceinline__ void gld_lds16(const unsigned short* g, unsigned short* l) {
  __builtin_amdgcn_global_load_lds(
      (const __attribute__((address_space(1))) unsigned int*)g,
      (__attribute__((address_space(3))) unsigned int*)l, 16, 0, 0);
}

__global__ __launch_bounds__(256, 2) void mgemm_kernel(
    const unsigned short* __restrict__ Ah, const unsigned short* __restrict__ Al,
    const unsigned short* __restrict__ Bh, const unsigned short* __restrict__ Bl,
    float* __restrict__ C0, float* __restrict__ C1, float* __restrict__ C2,
    int N, int mode)
{
  __shared__ __align__(16) unsigned short As[2 * 8 * 512];
  __shared__ __align__(16) unsigned short Bs[2 * 8 * 512];
  const int tid = threadIdx.x, lane = tid & 63, w = tid >> 6;
  const int mt0 = blockIdx.y << 3;
  const int nt0 = blockIdx.x << 3;

  f32x4 acc[4][4];
#pragma unroll
  for (int i = 0; i < 4; ++i)
#pragma unroll
    for (int j = 0; j < 4; ++j)
      acc[i][j] = (f32x4){0.f, 0.f, 0.f, 0.f};

  const int rA = (w >> 1) << 2, rB = (w & 1) << 2;

  for (int kc = 0; kc < 32; ++kc) {
#pragma unroll
    for (int li = 0; li < 8; ++li) {
      const int gi = (w << 3) | li;
      const int t = gi & 7, hl = (gi >> 3) & 1, mat = gi >> 4;
      const unsigned short* gbase = mat ? (hl ? Bl : Bh) : (hl ? Al : Ah);
      const int tg = (mat ? nt0 : mt0) + t;
      const unsigned short* g = gbase + (((size_t)(tg * 32 + kc) << 6) + lane) * 8;
      unsigned short* l = (mat ? Bs : As) + hl * 4096 + t * 512;
      gld_lds16(g, l);
    }
    __syncthreads();
    bf16x8 ah[4], al[4], bh[4], bl[4];
#pragma unroll
    for (int i = 0; i < 4; ++i) {
      ah[i] = *(const bf16x8*)&As[(rA + i) * 512 + lane * 8];
      al[i] = *(const bf16x8*)&As[4096 + (rA + i) * 512 + lane * 8];
      bh[i] = *(const bf16x8*)&Bs[(rB + i) * 512 + lane * 8];
      bl[i] = *(const bf16x8*)&Bs[4096 + (rB + i) * 512 + lane * 8];
    }
#pragma unroll
    for (int i = 0; i < 4; ++i)
#pragma unroll
      for (int j = 0; j < 4; ++j) {
        acc[i][j] = __builtin_amdgcn_mfma_f32_16x16x32_bf16(ah[i], bh[j], acc[i][j], 0, 0, 0);
        acc[i][j] = __builtin_amdgcn_mfma_f32_16x16x32_bf16(ah[i], bl[j], acc[i][j], 0, 0, 0);
        acc[i][j] = __builtin_amdgcn_mfma_f32_16x16x32_bf16(al[i], bh[j], acc[i][j], 0, 0, 0);
      }
    __syncthreads();
  }

  const int col = lane & 15, quad = lane >> 4;
  const int mbase = (blockIdx.y << 7) + ((w >> 1) << 6);
  const int nbase = (blockIdx.x << 7) + ((w & 1) << 6);
  if (mode == 0) {
    const int which = nbase >> 10;
    const int h = (nbase & 1023) >> 6;
    float* dst = (which == 0) ? C0 : (which == 1) ? C1 : C2;
    float* base = dst + (((size_t)h * T_DIM) << 6);
#pragma unroll
    for (int i = 0; i < 4; ++i)
#pragma unroll
      for (int j = 0; j < 4; ++j)
#pragma unroll
        for (int reg = 0; reg < 4; ++reg) {
          const int m = mbase + i * 16 + quad * 4 + reg;
          base[((size_t)m << 6) + j * 16 + col] = acc[i][j][reg];
        }
  } else if (mode == 1) {
#pragma unroll
    for (int i = 0; i < 4; ++i)
#pragma unroll
      for (int j = 0; j < 4; ++j)
#pragma unroll
        for (int reg = 0; reg < 4; ++reg) {
          const int m = mbase + i * 16 + quad * 4 + reg;
          float vv = acc[i][j][reg];
          C0[(size_t)m * N + nbase + j * 16 + col] = vv / (1.f + expf(-vv));
        }
  } else {
#pragma unroll
    for (int i = 0; i < 4; ++i)
#pragma unroll
      for (int j = 0; j < 4; ++j)
#pragma unroll
        for (int reg = 0; reg < 4; ++reg) {
          const int m = mbase + i * 16 + quad * 4 + reg;
          C0[(size_t)m * N + nbase + j * 16 + col] = acc[i][j][reg];
        }
  }
}

// ---------------- RoPE + bf16 hi/lo split into attention frag layout --------
__global__ __launch_bounds__(64) void prep_frag_kernel(float* __restrict__ buf) {
  const int lane = threadIdx.x;
  const int t16 = blockIdx.x, h = blockIdx.y;
  const int nr = lane & 15, quad = lane >> 4;
  const int t = (t16 << 4) + nr;
  const float* row = buf + ((size_t)(h * T_DIM + t) << 6);
  const int d0 = quad << 3;
  float4 a0 = *(const float4*)(row + d0);
  float4 a1 = *(const float4*)(row + d0 + 4);
  float4 b0 = *(const float4*)(row + 32 + d0);
  float4 b1 = *(const float4*)(row + 32 + d0 + 4);
  float x0[8] = {a0.x, a0.y, a0.z, a0.w, a1.x, a1.y, a1.z, a1.w};
  float x1[8] = {b0.x, b0.y, b0.z, b0.w, b1.x, b1.y, b1.z, b1.w};
  unsigned short h0[8], l0[8], h1[8], l1[8];
#pragma unroll
  for (int jj = 0; jj < 8; ++jj) {
    double invf = exp(-(double)(d0 + jj) * (log(10000.0) / 32.0));
    double ang = (double)t * invf;
    double cs = cos(ang), sn = sin(ang);
    float o0 = (float)((double)x0[jj] * cs - (double)x1[jj] * sn);
    float o1 = (float)((double)x1[jj] * cs + (double)x0[jj] * sn);
    unsigned short hb = bf16rn(o0);
    h0[jj] = hb;
    l0[jj] = bf16rn(o0 - __uint_as_float((unsigned)hb << 16));
    hb = bf16rn(o1);
    h1[jj] = hb;
    l1[jj] = bf16rn(o1 - __uint_as_float((unsigned)hb << 16));
  }
  char* base = (char*)buf + (((size_t)(h * 128 + t16)) << 12);
  uint4 v;
  v.x = (unsigned)h0[0] | ((unsigned)h0[1] << 16);
  v.y = (unsigned)h0[2] | ((unsigned)h0[3] << 16);
  v.z = (unsigned)h0[4] | ((unsigned)h0[5] << 16);
  v.w = (unsigned)h0[6] | ((unsigned)h0[7] << 16);
  ((uint4*)base)[lane] = v;
  v.x = (unsigned)h1[0] | ((unsigned)h1[1] << 16);
  v.y = (unsigned)h1[2] | ((unsigned)h1[3] << 16);
  v.z = (unsigned)h1[4] | ((unsigned)h1[5] << 16);
  v.w = (unsigned)h1[6] | ((unsigned)h1[7] << 16);
  ((uint4*)(base + 1024))[lane] = v;
  v.x = (unsigned)l0[0] | ((unsigned)l0[1] << 16);
  v.y = (unsigned)l0[2] | ((unsigned)l0[3] << 16);
  v.z = (unsigned)l0[4] | ((unsigned)l0[5] << 16);
  v.w = (unsigned)l0[6] | ((unsigned)l0[7] << 16);
  ((uint4*)(base + 2048))[lane] = v;
  v.x = (unsigned)l1[0] | ((unsigned)l1[1] << 16);
  v.y = (unsigned)l1[2] | ((unsigned)l1[3] << 16);
  v.z = (unsigned)l1[4] | ((unsigned)l1[5] << 16);
  v.w = (unsigned)l1[6] | ((unsigned)l1[7] << 16);
  ((uint4*)(base + 3072))[lane] = v;
}

// ---------------- attention ----------------
__device__ __forceinline__ unsigned f2u(float f) {
  unsigned u = __float_as_uint(f);
  return (u & 0x80000000u) ? ~u : (u | 0x80000000u);
}
__device__ __forceinline__ float u2f(unsigned u) {
  unsigned v = (u & 0x80000000u) ? (u & 0x7FFFFFFFu) : ~u;
  return __uint_as_float(v);
}
__device__ __forceinline__ bf16x8 ld_frag(const uint4* p) {
  uint4 u = *p;
  return __builtin_bit_cast(bf16x8, u);
}

__global__ __launch_bounds__(256) void attn_kernel(
    const float* __restrict__ qfrag, const float* __restrict__ kfrag,
    const float* __restrict__ v, const float* __restrict__ span_params,
    float* __restrict__ y)
{
  // union: phase A = s[QTILE][T_DIM] fp32 scores (32 KB);
  //        phase B = hist[4][256] (4 KB) + listIdx[4][128] (2 KB) + listW (2 KB)
  __shared__ __align__(16) char smem[QTILE * T_DIM * 4];
  float* sBase = (float*)smem;
  unsigned* histB = (unsigned*)smem;
  int* listIdxB = (int*)(smem + 4096);
  float* listWB = (float*)(smem + 6144);

  const int tid = threadIdx.x;
  const int lane = tid & 63;
  const int w = tid >> 6;
  const int q0 = blockIdx.x * QTILE;
  const int h = blockIdx.y;
  const int qi = q0 + w;
  const int n = qi + 1;
  const float* vh = v + (((size_t)h * T_DIM) << 6);

  // ---- scores via bf16-split MFMA ----
  const int qt = q0 >> 4;
  const int qsel = (q0 & 15) >> 2;
  {
    const uint4* qf = (const uint4*)((const char*)qfrag + (((size_t)(h * 128 + qt)) << 12));
    bf16x8 Ah0 = ld_frag(qf + lane);
    bf16x8 Ah1 = ld_frag(qf + 64 + lane);
    bf16x8 Al0 = ld_frag(qf + 128 + lane);
    bf16x8 Al1 = ld_frag(qf + 192 + lane);
    const int tfmax = (q0 + QTILE - 1) >> 4;
    for (int tf = w; tf <= tfmax; tf += 4) {
      const uint4* kf = (const uint4*)((const char*)kfrag + (((size_t)(h * 128 + tf)) << 12));
      bf16x8 Bh0 = ld_frag(kf + lane);
      bf16x8 Bh1 = ld_frag(kf + 64 + lane);
      bf16x8 Bl0 = ld_frag(kf + 128 + lane);
      bf16x8 Bl1 = ld_frag(kf + 192 + lane);
      f32x4 acc = {0.f, 0.f, 0.f, 0.f};
      acc = __builtin_amdgcn_mfma_f32_16x16x32_bf16(Ah0, Bh0, acc, 0, 0, 0);
      acc = __builtin_amdgcn_mfma_f32_16x16x32_bf16(Ah0, Bl0, acc, 0, 0, 0);
      acc = __builtin_amdgcn_mfma_f32_16x16x32_bf16(Al0, Bh0, acc, 0, 0, 0);
      acc = __builtin_amdgcn_mfma_f32_16x16x32_bf16(Ah1, Bh1, acc, 0, 0, 0);
      acc = __builtin_amdgcn_mfma_f32_16x16x32_bf16(Ah1, Bl1, acc, 0, 0, 0);
      acc = __builtin_amdgcn_mfma_f32_16x16x32_bf16(Al1, Bh1, acc, 0, 0, 0);
      if ((lane >> 4) == qsel) {
        const int jcol = (tf << 4) + (lane & 15);
#pragma unroll
        for (int r = 0; r < 4; ++r)
          if (jcol <= q0 + r) sBase[r * T_DIM + jcol] = acc[r] * 0.125f;
      }
    }
  }
  __syncthreads();

  // ---- cache this wave's score row in registers (constant indices) ----
  float sreg[32];
#pragma unroll
  for (int c = 0; c < 4; ++c) {
    if ((c << 9) < n) {
#pragma unroll
      for (int i = 0; i < 8; ++i) {
        const int j = (((c << 3) + i) << 6) + lane;
        sreg[(c << 3) + i] = (j < n) ? sBase[w * T_DIM + j] : -INFINITY;
      }
    } else {
#pragma unroll
      for (int i = 0; i < 8; ++i) sreg[(c << 3) + i] = -INFINITY;
    }
  }
  __syncthreads();   // s region dead; smem becomes hist/list

  // ---- row max (registers + shfl) ----
  float lm = -INFINITY;
#pragma unroll
  for (int i = 0; i < 32; ++i) lm = fmaxf(lm, sreg[i]);
#pragma unroll
  for (int off = 32; off > 0; off >>= 1)
    lm = fmaxf(lm, __shfl_xor(lm, off, 64));
  const float mrow = lm;

  // ---- exact rank-64 threshold: per-wave radix-256 select on sreg ----
  // OOB lanes hold -INF (u=0x007FFFFF, top byte 0x00 <-> |s|>1.7e38): can
  // never be the boundary bin, so no per-element bounds check needed.
  unsigned* hist = histB + (w << 8);
  float thresh = -INFINITY;
  if (n > TOPK_K) {
    unsigned prefix = 0;
    int want = TOPK_K;
#pragma unroll
    for (int shift = 24; shift >= 0; shift -= 8) {
      uint4 z4 = {0u, 0u, 0u, 0u};
      *(uint4*)&hist[lane << 2] = z4;
      __threadfence_block();
      const unsigned pm = (shift == 24) ? 0u : (0xFFFFFFFFu << (shift + 8));
#pragma unroll
      for (int c = 0; c < 4; ++c) {
        if ((c << 9) < n) {
#pragma unroll
          for (int i = 0; i < 8; ++i) {
            unsigned u = f2u(sreg[(c << 3) + i]);
            if ((u & pm) == prefix)
              atomicAdd(&hist[(u >> shift) & 255u], 1u);
          }
        }
      }
      __threadfence_block();
      uint4 hv = *(const uint4*)&hist[lane << 2];
      unsigned loc = hv.x + hv.y + hv.z + hv.w;
      unsigned suf = loc;
#pragma unroll
      for (int off = 1; off < 64; off <<= 1) {
        unsigned t = __shfl_down(suf, off, 64);
        suf += (lane + off < 64) ? t : 0u;
      }
      unsigned sufE = suf - loc;
      unsigned S3 = sufE + hv.w;
      unsigned S2 = S3 + hv.z;
      unsigned S1 = S2 + hv.y;
      unsigned S0 = S1 + hv.x;
      const unsigned wt = (unsigned)want;
      int found = 0;
      unsigned pk = 0;
      if (S0 >= wt && S1 < wt) { found = 1; pk = ((unsigned)(4 * lane + 0) << 16) | (wt - S1); }
      if (S1 >= wt && S2 < wt) { found = 1; pk = ((unsigned)(4 * lane + 1) << 16) | (wt - S2); }
      if (S2 >= wt && S3 < wt) { found = 1; pk = ((unsigned)(4 * lane + 2) << 16) | (wt - S3); }
      if (S3 >= wt && sufE < wt) { found = 1; pk = ((unsigned)(4 * lane + 3) << 16) | (wt - sufE); }
      unsigned long long mk = __ballot(found);
      int src = __ffsll(mk) - 1;
      pk = __shfl(pk, src, 64);
      prefix |= (pk >> 16) << shift;
      want = (int)(pk & 0xFFFFu);
    }
    thresh = u2f(prefix);
  }

  // ---- weights on sreg: topk softmax + span mask + Z/U + ballot append ----
  const float span = 2048.f * fminf(fmaxf(span_params[h], 0.f), 1.f);
  int* listIdx = listIdxB + w * LCAP;
  float* listW = listWB + w * LCAP;
  float Zl = 0.f, Ul = 0.f;
  int cnt_run = 0;
#pragma unroll
  for (int c = 0; c < 4; ++c) {
    if ((c << 9) < n) {
#pragma unroll
      for (int i = 0; i < 8; ++i) {
        const int j = (((c << 3) + i) << 6) + lane;
        const float sv = sreg[(c << 3) + i];
        float wv = 0.f, wm = 0.f;
        bool keep = false;
        if (sv >= thresh) {
          wv = __expf(sv - mrow);
          float dist = (float)(qi - j);
          float msk = fminf(fmaxf((32.f + span - dist) * (1.f / 32.f), 0.f), 1.f);
          wm = wv * msk;
          keep = wm > 0.f;
        }
        Zl += wv;
        Ul += wm;
        unsigned long long mb = __ballot(keep);
        if (keep) {
          int pos = cnt_run + (int)__popcll(mb & ((1ull << lane) - 1ull));
          if (pos < LCAP) { listIdx[pos] = j; listW[pos] = wm; }
        }
        cnt_run += (int)__popcll(mb);
      }
    }
  }
#pragma unroll
  for (int off = 32; off > 0; off >>= 1) {
    Zl += __shfl_xor(Zl, off, 64);
    Ul += __shfl_xor(Ul, off, 64);
  }
  const float scale = 1.f / (Ul + 1e-8f * Zl);
  __threadfence_block();
  const int cnt = min(cnt_run, LCAP);

  // ---- PV over kept list: 4 rows x 16 dim-groups per iteration ----
  const int g = lane >> 4;
  const int d4 = (lane & 15) << 2;
  float4 acc4 = {0.f, 0.f, 0.f, 0.f};
  for (int e0 = 0; e0 < cnt; e0 += 4) {
    int e = e0 + g;
    float wm = 0.f;
    int idx = 0;
    if (e < cnt) { idx = listIdx[e]; wm = listW[e]; }
    const float4 vv = *(const float4*)(vh + ((size_t)idx << 6) + d4);
    acc4.x = fmaf(wm, vv.x, acc4.x);
    acc4.y = fmaf(wm, vv.y, acc4.y);
    acc4.z = fmaf(wm, vv.z, acc4.z);
    acc4.w = fmaf(wm, vv.w, acc4.w);
  }
#pragma unroll
  for (int off = 16; off <= 32; off <<= 1) {
    acc4.x += __shfl_xor(acc4.x, off, 64);
    acc4.y += __shfl_xor(acc4.y, off, 64);
    acc4.z += __shfl_xor(acc4.z, off, 64);
    acc4.w += __shfl_xor(acc4.w, off, 64);
  }
  if (g == 0) {
    float4 o = {acc4.x * scale, acc4.y * scale, acc4.z * scale, acc4.w * scale};
    *(float4*)(y + ((((size_t)h * T_DIM) + qi) << 6) + d4) = o;
  }
}

// -------- gating: y_att (head-major) * gate -> ygf frag-global hi/lo --------
__global__ __launch_bounds__(256) void gate_mul_frag_kernel(
    const float* __restrict__ y_att, const float* __restrict__ gate,
    unsigned short* __restrict__ Yh, unsigned short* __restrict__ Yl)
{
  const int tid = blockIdx.x * 256 + threadIdx.x;
  const int k8 = tid & 127, r = tid >> 7;
  const int c0 = k8 << 3;
  const int h = c0 >> 6, d0 = c0 & 63;
  const float* ya = y_att + ((size_t)(h * T_DIM + r) << 6) + d0;
  const float* ga = gate + ((size_t)r << 10) + c0;
  float4 y0 = *(const float4*)ya;
  float4 y1 = *(const float4*)(ya + 4);
  float4 g0 = *(const float4*)ga;
  float4 g1 = *(const float4*)(ga + 4);
  float p[8] = {y0.x * g0.x, y0.y * g0.y, y0.z * g0.z, y0.w * g0.w,
                y1.x * g1.x, y1.y * g1.y, y1.z * g1.z, y1.w * g1.w};
  unsigned hi[8], lo[8];
#pragma unroll
  for (int jj = 0; jj < 8; ++jj) {
    unsigned short hb = bf16rn(p[jj]);
    hi[jj] = hb;
    lo[jj] = bf16rn(p[jj] - __uint_as_float((unsigned)hb << 16));
  }
  const int t16 = r >> 4, rr = r & 15, kc = k8 >> 2, kq = k8 & 3;
  const size_t elem = (((size_t)(t16 * 32 + kc)) * 64 + ((kq << 4) | rr)) * 8;
  uint4 vh, vl;
  vh.x = hi[0] | (hi[1] << 16); vh.y = hi[2] | (hi[3] << 16);
  vh.z = hi[4] | (hi[5] << 16); vh.w = hi[6] | (hi[7] << 16);
  vl.x = lo[0] | (lo[1] << 16); vl.y = lo[2] | (lo[3] << 16);
  vl.z = lo[4] | (lo[5] << 16); vl.w = lo[6] | (lo[7] << 16);
  *(uint4*)(Yh + elem) = vh;
  *(uint4*)(Yl + elem) = vl;
}

extern "C" void kernel_launch(void* const* d_in, const int* in_sizes, int n_in,
                              void* d_out, int out_size, void* d_ws, size_t ws_size,
                              hipStream_t stream) {
  (void)in_sizes; (void)n_in; (void)out_size; (void)ws_size;
  const float* x           = (const float*)d_in[0];
  const float* w_attn      = (const float*)d_in[1];
  const float* w_proj      = (const float*)d_in[2];
  const float* w_gate      = (const float*)d_in[3];
  const float* span_params = (const float*)d_in[4];
  float* out = (float*)d_out;

  char* ws = (char*)d_ws;
  const size_t MB = 1024 * 1024;
  float* q     = (float*)(ws);            // 8 MB
  float* k     = (float*)(ws + 8 * MB);   // 8 MB
  float* v     = (float*)(ws + 16 * MB);  // 8 MB
  float* gate  = (float*)(ws + 24 * MB);  // 8 MB
  float* y_att = (float*)(ws + 32 * MB);  // 8 MB
  unsigned short* xf_h  = (unsigned short*)(ws + 40 * MB);  // 4 MB
  unsigned short* xf_l  = (unsigned short*)(ws + 44 * MB);  // 4 MB
  unsigned short* wfa_h = (unsigned short*)(ws + 48 * MB);  // 6 MB
  unsigned short* wfa_l = (unsigned short*)(ws + 54 * MB);  // 6 MB
  unsigned short* wfg_h = (unsigned short*)(ws + 60 * MB);  // 2 MB
  unsigned short* wfg_l = (unsigned short*)(ws + 62 * MB);  // 2 MB
  unsigned short* wfp_h = (unsigned short*)(ws + 64 * MB);  // 2 MB
  unsigned short* wfp_l = (unsigned short*)(ws + 66 * MB);  // 2 MB
  unsigned short* ygf_h = (unsigned short*)(ws + 68 * MB);  // 4 MB
  unsigned short* ygf_l = (unsigned short*)(ws + 72 * MB);  // 4 MB

  convert_frag_kernel<<<T_DIM / 2, 256, 0, stream>>>(x, xf_h, xf_l);
  convert_frag_kernel<<<3 * C_DIM / 2, 256, 0, stream>>>(w_attn, wfa_h, wfa_l);
  convert_frag_kernel<<<C_DIM / 2, 256, 0, stream>>>(w_gate, wfg_h, wfg_l);
  convert_frag_kernel<<<C_DIM / 2, 256, 0, stream>>>(w_proj, wfp_h, wfp_l);

  mgemm_kernel<<<dim3(3 * C_DIM / 128, T_DIM / 128), 256, 0, stream>>>(
      xf_h, xf_l, wfa_h, wfa_l, q, k, v, 3 * C_DIM, 0);
  prep_frag_kernel<<<dim3(T_DIM / 16, H_DIM), 64, 0, stream>>>(q);
  prep_frag_kernel<<<dim3(T_DIM / 16, H_DIM), 64, 0, stream>>>(k);
  mgemm_kernel<<<dim3(C_DIM / 128, T_DIM / 128), 256, 0, stream>>>(
      xf_h, xf_l, wfg_h, wfg_l, gate, nullptr, nullptr, C_DIM, 1);
  attn_kernel<<<dim3(T_DIM / QTILE, H_DIM), 256, 0, stream>>>(
      q, k, v, span_params, y_att);
  gate_mul_frag_kernel<<<T_DIM / 2, 256, 0, stream>>>(y_att, gate, ygf_h, ygf_l);
  mgemm_kernel<<<dim3(C_DIM / 128, T_DIM / 128), 256, 0, stream>>>(
      ygf_h, ygf_l, wfp_h, wfp_l, out, nullptr, nullptr, C_DIM, 2);
}

// Round 7
// 387.252 us; speedup vs baseline: 9.3048x; 1.1843x over previous
//
#include <hip/hip_runtime.h>
#include <math.h>

#define T_DIM 2048
#define C_DIM 1024
#define H_DIM 16
#define HD 64
#define TOPK_K 64
#define QTILE 4
#define LCAP 128

typedef __attribute__((ext_vector_type(8))) __bf16 bf16x8;
typedef __attribute__((ext_vector_type(4))) float f32x4;

__device__ __forceinline__ unsigned short bf16rn(float x) {
  unsigned u = __float_as_uint(x);
  return (unsigned short)((u + 0x7FFFu + ((u >> 16) & 1u)) >> 16);
}

// ------- fused fp32 -> frag-global bf16 hi/lo converter (all 4 matrices) ----
// rows: [0,2048)=x -> xf; [2048,6144)=concat(w_attn,w_gate) -> wqg;
//       [6144,7168)=w_proj -> wfp
__global__ __launch_bounds__(256) void convert_all_kernel(
    const float* __restrict__ x, const float* __restrict__ wa,
    const float* __restrict__ wg, const float* __restrict__ wp,
    unsigned short* __restrict__ xh, unsigned short* __restrict__ xl,
    unsigned short* __restrict__ wqgh, unsigned short* __restrict__ wqgl,
    unsigned short* __restrict__ wph, unsigned short* __restrict__ wpl)
{
  const int tid = blockIdx.x * 256 + threadIdx.x;
  const int k8 = tid & 127, r = tid >> 7;
  const float* src;
  unsigned short *Dh, *Dl;
  int srow, drow;
  if (r < 2048)      { src = x;  Dh = xh;   Dl = xl;   srow = r;        drow = r; }
  else if (r < 5120) { src = wa; Dh = wqgh; Dl = wqgl; srow = r - 2048; drow = r - 2048; }
  else if (r < 6144) { src = wg; Dh = wqgh; Dl = wqgl; srow = r - 5120; drow = r - 2048; }
  else               { src = wp; Dh = wph;  Dl = wpl;  srow = r - 6144; drow = r - 6144; }
  const float* s = src + ((size_t)srow << 10) + (k8 << 3);
  float4 a = *(const float4*)s;
  float4 b = *(const float4*)(s + 4);
  float xs[8] = {a.x, a.y, a.z, a.w, b.x, b.y, b.z, b.w};
  unsigned hi[8], lo[8];
#pragma unroll
  for (int jj = 0; jj < 8; ++jj) {
    unsigned short hb = bf16rn(xs[jj]);
    hi[jj] = hb;
    lo[jj] = bf16rn(xs[jj] - __uint_as_float((unsigned)hb << 16));
  }
  const int t16 = drow >> 4, rr = drow & 15, kc = k8 >> 2, kq = k8 & 3;
  const size_t elem = (((size_t)(t16 * 32 + kc)) * 64 + ((kq << 4) | rr)) * 8;
  uint4 vh, vl;
  vh.x = hi[0] | (hi[1] << 16); vh.y = hi[2] | (hi[3] << 16);
  vh.z = hi[4] | (hi[5] << 16); vh.w = hi[6] | (hi[7] << 16);
  vl.x = lo[0] | (lo[1] << 16); vl.y = lo[2] | (lo[3] << 16);
  vl.z = lo[4] | (lo[5] << 16); vl.w = lo[6] | (lo[7] << 16);
  *(uint4*)(Dh + elem) = vh;
  *(uint4*)(Dl + elem) = vl;
}

// ---------------- split-bf16 MFMA GEMM machinery ----------------
__device__ __forceinline__ void gld_lds16(const unsigned short* g, unsigned short* l) {
  __builtin_amdgcn_global_load_lds(
      (const __attribute__((address_space(1))) unsigned int*)g,
      (__attribute__((address_space(3))) unsigned int*)l, 16, 0, 0);
}

// C = A[2048][1024] @ B[4096][1024]^T fused epilogue:
// N-quadrant 0/1/2 -> head-major q/k/v fp32; quadrant 3 -> silu -> gate row-major.
__global__ __launch_bounds__(256, 2) void mgemm_qkvg_kernel(
    const unsigned short* __restrict__ Ah, const unsigned short* __restrict__ Al,
    const unsigned short* __restrict__ Bh, const unsigned short* __restrict__ Bl,
    float* __restrict__ Cq, float* __restrict__ Ck, float* __restrict__ Cv,
    float* __restrict__ Cg)
{
  __shared__ __align__(16) unsigned short As[2 * 8 * 512];
  __shared__ __align__(16) unsigned short Bs[2 * 8 * 512];
  const int tid = threadIdx.x, lane = tid & 63, w = tid >> 6;
  const int mt0 = blockIdx.y << 3;
  const int nt0 = blockIdx.x << 3;

  f32x4 acc[4][4];
#pragma unroll
  for (int i = 0; i < 4; ++i)
#pragma unroll
    for (int j = 0; j < 4; ++j)
      acc[i][j] = (f32x4){0.f, 0.f, 0.f, 0.f};

  const int rA = (w >> 1) << 2, rB = (w & 1) << 2;

  for (int kc = 0; kc < 32; ++kc) {
#pragma unroll
    for (int li = 0; li < 8; ++li) {
      const int gi = (w << 3) | li;
      const int t = gi & 7, hl = (gi >> 3) & 1, mat = gi >> 4;
      const unsigned short* gbase = mat ? (hl ? Bl : Bh) : (hl ? Al : Ah);
      const int tg = (mat ? nt0 : mt0) + t;
      const unsigned short* g = gbase + (((size_t)(tg * 32 + kc) << 6) + lane) * 8;
      unsigned short* l = (mat ? Bs : As) + hl * 4096 + t * 512;
      gld_lds16(g, l);
    }
    __syncthreads();
    bf16x8 ah[4], al[4], bh[4], bl[4];
#pragma unroll
    for (int i = 0; i < 4; ++i) {
      ah[i] = *(const bf16x8*)&As[(rA + i) * 512 + lane * 8];
      al[i] = *(const bf16x8*)&As[4096 + (rA + i) * 512 + lane * 8];
      bh[i] = *(const bf16x8*)&Bs[(rB + i) * 512 + lane * 8];
      bl[i] = *(const bf16x8*)&Bs[4096 + (rB + i) * 512 + lane * 8];
    }
#pragma unroll
    for (int i = 0; i < 4; ++i)
#pragma unroll
      for (int j = 0; j < 4; ++j) {
        acc[i][j] = __builtin_amdgcn_mfma_f32_16x16x32_bf16(ah[i], bh[j], acc[i][j], 0, 0, 0);
        acc[i][j] = __builtin_amdgcn_mfma_f32_16x16x32_bf16(ah[i], bl[j], acc[i][j], 0, 0, 0);
        acc[i][j] = __builtin_amdgcn_mfma_f32_16x16x32_bf16(al[i], bh[j], acc[i][j], 0, 0, 0);
      }
    __syncthreads();
  }

  const int col = lane & 15, quad = lane >> 4;
  const int mbase = (blockIdx.y << 7) + ((w >> 1) << 6);
  const int nbase = (blockIdx.x << 7) + ((w & 1) << 6);
  const int which = nbase >> 10;
  if (which < 3) {
    const int h = (nbase & 1023) >> 6;
    float* dst = (which == 0) ? Cq : (which == 1) ? Ck : Cv;
    float* base = dst + (((size_t)h * T_DIM) << 6);
#pragma unroll
    for (int i = 0; i < 4; ++i)
#pragma unroll
      for (int j = 0; j < 4; ++j)
#pragma unroll
        for (int reg = 0; reg < 4; ++reg) {
          const int m = mbase + i * 16 + quad * 4 + reg;
          base[((size_t)m << 6) + j * 16 + col] = acc[i][j][reg];
        }
  } else {
    const int cb = nbase & 1023;
#pragma unroll
    for (int i = 0; i < 4; ++i)
#pragma unroll
      for (int j = 0; j < 4; ++j)
#pragma unroll
        for (int reg = 0; reg < 4; ++reg) {
          const int m = mbase + i * 16 + quad * 4 + reg;
          float vv = acc[i][j][reg];
          Cg[((size_t)m << 10) + cb + j * 16 + col] = vv / (1.f + expf(-vv));
        }
  }
}

// proj GEMM, split-K: C = A[2048][1024] @ B[1024][1024]^T, kc in [kc0,kc0+16)
__global__ __launch_bounds__(256, 2) void mgemm_proj_kernel(
    const unsigned short* __restrict__ Ah, const unsigned short* __restrict__ Al,
    const unsigned short* __restrict__ Bh, const unsigned short* __restrict__ Bl,
    float* __restrict__ P0, float* __restrict__ P1)
{
  __shared__ __align__(16) unsigned short As[2 * 8 * 512];
  __shared__ __align__(16) unsigned short Bs[2 * 8 * 512];
  const int tid = threadIdx.x, lane = tid & 63, w = tid >> 6;
  const int mt0 = blockIdx.y << 3;
  const int nt0 = blockIdx.x << 3;
  const int kc0 = blockIdx.z << 4;
  float* Cout = blockIdx.z ? P1 : P0;

  f32x4 acc[4][4];
#pragma unroll
  for (int i = 0; i < 4; ++i)
#pragma unroll
    for (int j = 0; j < 4; ++j)
      acc[i][j] = (f32x4){0.f, 0.f, 0.f, 0.f};

  const int rA = (w >> 1) << 2, rB = (w & 1) << 2;

  for (int kc = kc0; kc < kc0 + 16; ++kc) {
#pragma unroll
    for (int li = 0; li < 8; ++li) {
      const int gi = (w << 3) | li;
      const int t = gi & 7, hl = (gi >> 3) & 1, mat = gi >> 4;
      const unsigned short* gbase = mat ? (hl ? Bl : Bh) : (hl ? Al : Ah);
      const int tg = (mat ? nt0 : mt0) + t;
      const unsigned short* g = gbase + (((size_t)(tg * 32 + kc) << 6) + lane) * 8;
      unsigned short* l = (mat ? Bs : As) + hl * 4096 + t * 512;
      gld_lds16(g, l);
    }
    __syncthreads();
    bf16x8 ah[4], al[4], bh[4], bl[4];
#pragma unroll
    for (int i = 0; i < 4; ++i) {
      ah[i] = *(const bf16x8*)&As[(rA + i) * 512 + lane * 8];
      al[i] = *(const bf16x8*)&As[4096 + (rA + i) * 512 + lane * 8];
      bh[i] = *(const bf16x8*)&Bs[(rB + i) * 512 + lane * 8];
      bl[i] = *(const bf16x8*)&Bs[4096 + (rB + i) * 512 + lane * 8];
    }
#pragma unroll
    for (int i = 0; i < 4; ++i)
#pragma unroll
      for (int j = 0; j < 4; ++j) {
        acc[i][j] = __builtin_amdgcn_mfma_f32_16x16x32_bf16(ah[i], bh[j], acc[i][j], 0, 0, 0);
        acc[i][j] = __builtin_amdgcn_mfma_f32_16x16x32_bf16(ah[i], bl[j], acc[i][j], 0, 0, 0);
        acc[i][j] = __builtin_amdgcn_mfma_f32_16x16x32_bf16(al[i], bh[j], acc[i][j], 0, 0, 0);
      }
    __syncthreads();
  }

  const int col = lane & 15, quad = lane >> 4;
  const int mbase = (blockIdx.y << 7) + ((w >> 1) << 6);
  const int nbase = (blockIdx.x << 7) + ((w & 1) << 6);
#pragma unroll
  for (int i = 0; i < 4; ++i)
#pragma unroll
    for (int j = 0; j < 4; ++j)
#pragma unroll
      for (int reg = 0; reg < 4; ++reg) {
        const int m = mbase + i * 16 + quad * 4 + reg;
        Cout[((size_t)m << 10) + nbase + j * 16 + col] = acc[i][j][reg];
      }
}

__global__ __launch_bounds__(256) void add2_kernel(
    const float* __restrict__ P0, const float* __restrict__ P1,
    float* __restrict__ out)
{
  const int i = (blockIdx.x * 256 + threadIdx.x) << 2;
  float4 a = *(const float4*)(P0 + i);
  float4 b = *(const float4*)(P1 + i);
  float4 o = {a.x + b.x, a.y + b.y, a.z + b.z, a.w + b.w};
  *(float4*)(out + i) = o;
}

// ------- RoPE + bf16 hi/lo split into attention frag layout (q and k) -------
__global__ __launch_bounds__(64) void prep_frag_kernel(
    float* __restrict__ qb, float* __restrict__ kb)
{
  float* buf = blockIdx.z ? kb : qb;
  const int lane = threadIdx.x;
  const int t16 = blockIdx.x, h = blockIdx.y;
  const int nr = lane & 15, quad = lane >> 4;
  const int t = (t16 << 4) + nr;
  const float* row = buf + ((size_t)(h * T_DIM + t) << 6);
  const int d0 = quad << 3;
  float4 a0 = *(const float4*)(row + d0);
  float4 a1 = *(const float4*)(row + d0 + 4);
  float4 b0 = *(const float4*)(row + 32 + d0);
  float4 b1 = *(const float4*)(row + 32 + d0 + 4);
  float x0[8] = {a0.x, a0.y, a0.z, a0.w, a1.x, a1.y, a1.z, a1.w};
  float x1[8] = {b0.x, b0.y, b0.z, b0.w, b1.x, b1.y, b1.z, b1.w};
  unsigned short h0[8], l0[8], h1[8], l1[8];
#pragma unroll
  for (int jj = 0; jj < 8; ++jj) {
    double invf = exp(-(double)(d0 + jj) * (log(10000.0) / 32.0));
    double ang = (double)t * invf;
    double cs = cos(ang), sn = sin(ang);
    float o0 = (float)((double)x0[jj] * cs - (double)x1[jj] * sn);
    float o1 = (float)((double)x1[jj] * cs + (double)x0[jj] * sn);
    unsigned short hb = bf16rn(o0);
    h0[jj] = hb;
    l0[jj] = bf16rn(o0 - __uint_as_float((unsigned)hb << 16));
    hb = bf16rn(o1);
    h1[jj] = hb;
    l1[jj] = bf16rn(o1 - __uint_as_float((unsigned)hb << 16));
  }
  char* base = (char*)buf + (((size_t)(h * 128 + t16)) << 12);
  uint4 v;
  v.x = (unsigned)h0[0] | ((unsigned)h0[1] << 16);
  v.y = (unsigned)h0[2] | ((unsigned)h0[3] << 16);
  v.z = (unsigned)h0[4] | ((unsigned)h0[5] << 16);
  v.w = (unsigned)h0[6] | ((unsigned)h0[7] << 16);
  ((uint4*)base)[lane] = v;
  v.x = (unsigned)h1[0] | ((unsigned)h1[1] << 16);
  v.y = (unsigned)h1[2] | ((unsigned)h1[3] << 16);
  v.z = (unsigned)h1[4] | ((unsigned)h1[5] << 16);
  v.w = (unsigned)h1[6] | ((unsigned)h1[7] << 16);
  ((uint4*)(base + 1024))[lane] = v;
  v.x = (unsigned)l0[0] | ((unsigned)l0[1] << 16);
  v.y = (unsigned)l0[2] | ((unsigned)l0[3] << 16);
  v.z = (unsigned)l0[4] | ((unsigned)l0[5] << 16);
  v.w = (unsigned)l0[6] | ((unsigned)l0[7] << 16);
  ((uint4*)(base + 2048))[lane] = v;
  v.x = (unsigned)l1[0] | ((unsigned)l1[1] << 16);
  v.y = (unsigned)l1[2] | ((unsigned)l1[3] << 16);
  v.z = (unsigned)l1[4] | ((unsigned)l1[5] << 16);
  v.w = (unsigned)l1[6] | ((unsigned)l1[7] << 16);
  ((uint4*)(base + 3072))[lane] = v;
}

// ---------------- attention ----------------
__device__ __forceinline__ unsigned f2u(float f) {
  unsigned u = __float_as_uint(f);
  return (u & 0x80000000u) ? ~u : (u | 0x80000000u);
}
__device__ __forceinline__ float u2f(unsigned u) {
  unsigned v = (u & 0x80000000u) ? (u & 0x7FFFFFFFu) : ~u;
  return __uint_as_float(v);
}
__device__ __forceinline__ bf16x8 ld_frag(const uint4* p) {
  uint4 u = *p;
  return __builtin_bit_cast(bf16x8, u);
}
#define PAD_KEY 0x007FFFFFu   // f2u(-INF); real scores always exceed this

__global__ __launch_bounds__(256) void attn_kernel(
    const float* __restrict__ qfrag, const float* __restrict__ kfrag,
    const float* __restrict__ v, const float* __restrict__ span_params,
    float* __restrict__ y)
{
  __shared__ __align__(16) char smem[QTILE * T_DIM * 4];
  float* sBase = (float*)smem;
  unsigned* histB = (unsigned*)smem;
  int* listIdxB = (int*)(smem + 4096);
  float* listWB = (float*)(smem + 6144);

  const int tid = threadIdx.x;
  const int lane = tid & 63;
  const int w = tid >> 6;
  const int q0 = blockIdx.x * QTILE;
  const int h = blockIdx.y;
  const int qi = q0 + w;
  const int n = qi + 1;
  const float* vh = v + (((size_t)h * T_DIM) << 6);

  // ---- scores via bf16-split MFMA ----
  const int qt = q0 >> 4;
  const int qsel = (q0 & 15) >> 2;
  {
    const uint4* qf = (const uint4*)((const char*)qfrag + (((size_t)(h * 128 + qt)) << 12));
    bf16x8 Ah0 = ld_frag(qf + lane);
    bf16x8 Ah1 = ld_frag(qf + 64 + lane);
    bf16x8 Al0 = ld_frag(qf + 128 + lane);
    bf16x8 Al1 = ld_frag(qf + 192 + lane);
    const int tfmax = (q0 + QTILE - 1) >> 4;
    for (int tf = w; tf <= tfmax; tf += 4) {
      const uint4* kf = (const uint4*)((const char*)kfrag + (((size_t)(h * 128 + tf)) << 12));
      bf16x8 Bh0 = ld_frag(kf + lane);
      bf16x8 Bh1 = ld_frag(kf + 64 + lane);
      bf16x8 Bl0 = ld_frag(kf + 128 + lane);
      bf16x8 Bl1 = ld_frag(kf + 192 + lane);
      f32x4 acc = {0.f, 0.f, 0.f, 0.f};
      acc = __builtin_amdgcn_mfma_f32_16x16x32_bf16(Ah0, Bh0, acc, 0, 0, 0);
      acc = __builtin_amdgcn_mfma_f32_16x16x32_bf16(Ah0, Bl0, acc, 0, 0, 0);
      acc = __builtin_amdgcn_mfma_f32_16x16x32_bf16(Al0, Bh0, acc, 0, 0, 0);
      acc = __builtin_amdgcn_mfma_f32_16x16x32_bf16(Ah1, Bh1, acc, 0, 0, 0);
      acc = __builtin_amdgcn_mfma_f32_16x16x32_bf16(Ah1, Bl1, acc, 0, 0, 0);
      acc = __builtin_amdgcn_mfma_f32_16x16x32_bf16(Al1, Bh1, acc, 0, 0, 0);
      if ((lane >> 4) == qsel) {
        const int jcol = (tf << 4) + (lane & 15);
#pragma unroll
        for (int r = 0; r < 4; ++r)
          if (jcol <= q0 + r) sBase[r * T_DIM + jcol] = acc[r] * 0.125f;
      }
    }
  }
  __syncthreads();

  // ---- cache this wave's score row as order-preserving uint keys ----
  unsigned ukey[32];
#pragma unroll
  for (int c = 0; c < 4; ++c) {
    if ((c << 9) < n) {
#pragma unroll
      for (int i = 0; i < 8; ++i) {
        const int j = (((c << 3) + i) << 6) + lane;
        ukey[(c << 3) + i] = (j < n) ? f2u(sBase[w * T_DIM + j]) : PAD_KEY;
      }
    } else {
#pragma unroll
      for (int i = 0; i < 8; ++i) ukey[(c << 3) + i] = PAD_KEY;
    }
  }
  __syncthreads();   // s region dead; smem becomes hist/list

  // ---- row max (integer keys, monotone) ----
  unsigned umax = 0;
#pragma unroll
  for (int i = 0; i < 32; ++i) umax = max(umax, ukey[i]);
#pragma unroll
  for (int off = 32; off > 0; off >>= 1)
    umax = max(umax, (unsigned)__shfl_xor((int)umax, off, 64));
  const float mrow = u2f(umax);

  // ---- exact rank-64 threshold: per-wave radix-256 select on ukey ----
  unsigned* hist = histB + (w << 8);
  unsigned thresh_u = 0;
  if (n > TOPK_K) {
    unsigned prefix = 0;
    int want = TOPK_K;
#pragma unroll
    for (int shift = 24; shift >= 0; shift -= 8) {
      uint4 z4 = {0u, 0u, 0u, 0u};
      *(uint4*)&hist[lane << 2] = z4;
      __threadfence_block();
      const unsigned pm = (shift == 24) ? 0u : (0xFFFFFFFFu << (shift + 8));
#pragma unroll
      for (int c = 0; c < 4; ++c) {
        if ((c << 9) < n) {
#pragma unroll
          for (int i = 0; i < 8; ++i) {
            const unsigned u = ukey[(c << 3) + i];
            if (u > PAD_KEY && (u & pm) == prefix)   // guard kills bin-0 hot-spot
              atomicAdd(&hist[(u >> shift) & 255u], 1u);
          }
        }
      }
      __threadfence_block();
      uint4 hv = *(const uint4*)&hist[lane << 2];
      unsigned loc = hv.x + hv.y + hv.z + hv.w;
      unsigned suf = loc;
#pragma unroll
      for (int off = 1; off < 64; off <<= 1) {
        unsigned t = __shfl_down(suf, off, 64);
        suf += (lane + off < 64) ? t : 0u;
      }
      unsigned sufE = suf - loc;
      unsigned S3 = sufE + hv.w;
      unsigned S2 = S3 + hv.z;
      unsigned S1 = S2 + hv.y;
      unsigned S0 = S1 + hv.x;
      const unsigned wt = (unsigned)want;
      int found = 0;
      unsigned pk = 0;
      if (S0 >= wt && S1 < wt) { found = 1; pk = ((unsigned)(4 * lane + 0) << 16) | (wt - S1); }
      if (S1 >= wt && S2 < wt) { found = 1; pk = ((unsigned)(4 * lane + 1) << 16) | (wt - S2); }
      if (S2 >= wt && S3 < wt) { found = 1; pk = ((unsigned)(4 * lane + 2) << 16) | (wt - S3); }
      if (S3 >= wt && sufE < wt) { found = 1; pk = ((unsigned)(4 * lane + 3) << 16) | (wt - sufE); }
      unsigned long long mk = __ballot(found);
      int src = __ffsll(mk) - 1;
      pk = __shfl(pk, src, 64);
      prefix |= (pk >> 16) << shift;
      want = (int)(pk & 0xFFFFu);
    }
    thresh_u = prefix;
  }

  // ---- weights: topk softmax + span mask + Z/U + ballot append ----
  const float span = 2048.f * fminf(fmaxf(span_params[h], 0.f), 1.f);
  int* listIdx = listIdxB + w * LCAP;
  float* listW = listWB + w * LCAP;
  float Zl = 0.f, Ul = 0.f;
  int cnt_run = 0;
#pragma unroll
  for (int c = 0; c < 4; ++c) {
    if ((c << 9) < n) {
#pragma unroll
      for (int i = 0; i < 8; ++i) {
        const int j = (((c << 3) + i) << 6) + lane;
        const unsigned u = ukey[(c << 3) + i];
        float wv = 0.f, wm = 0.f;
        bool keep = false;
        if (u >= thresh_u) {
          const float sv = u2f(u);
          wv = __expf(sv - mrow);
          float dist = (float)(qi - j);
          float msk = fminf(fmaxf((32.f + span - dist) * (1.f / 32.f), 0.f), 1.f);
          wm = wv * msk;
          keep = wm > 0.f;
        }
        Zl += wv;
        Ul += wm;
        unsigned long long mb = __ballot(keep);
        if (keep) {
          int pos = cnt_run + (int)__popcll(mb & ((1ull << lane) - 1ull));
          if (pos < LCAP) { listIdx[pos] = j; listW[pos] = wm; }
        }
        cnt_run += (int)__popcll(mb);
      }
    }
  }
#pragma unroll
  for (int off = 32; off > 0; off >>= 1) {
    Zl += __shfl_xor(Zl, off, 64);
    Ul += __shfl_xor(Ul, off, 64);
  }
  const float scale = 1.f / (Ul + 1e-8f * Zl);
  __threadfence_block();
  const int cnt = min(cnt_run, LCAP);

  // ---- PV over kept list: 4 rows x 16 dim-groups per iteration ----
  const int g = lane >> 4;
  const int d4 = (lane & 15) << 2;
  float4 acc4 = {0.f, 0.f, 0.f, 0.f};
  for (int e0 = 0; e0 < cnt; e0 += 4) {
    int e = e0 + g;
    float wm = 0.f;
    int idx = 0;
    if (e < cnt) { idx = listIdx[e]; wm = listW[e]; }
    const float4 vv = *(const float4*)(vh + ((size_t)idx << 6) + d4);
    acc4.x = fmaf(wm, vv.x, acc4.x);
    acc4.y = fmaf(wm, vv.y, acc4.y);
    acc4.z = fmaf(wm, vv.z, acc4.z);
    acc4.w = fmaf(wm, vv.w, acc4.w);
  }
#pragma unroll
  for (int off = 16; off <= 32; off <<= 1) {
    acc4.x += __shfl_xor(acc4.x, off, 64);
    acc4.y += __shfl_xor(acc4.y, off, 64);
    acc4.z += __shfl_xor(acc4.z, off, 64);
    acc4.w += __shfl_xor(acc4.w, off, 64);
  }
  if (g == 0) {
    float4 o = {acc4.x * scale, acc4.y * scale, acc4.z * scale, acc4.w * scale};
    *(float4*)(y + ((((size_t)h * T_DIM) + qi) << 6) + d4) = o;
  }
}

// -------- gating: y_att (head-major) * gate -> ygf frag-global hi/lo --------
__global__ __launch_bounds__(256) void gate_mul_frag_kernel(
    const float* __restrict__ y_att, const float* __restrict__ gate,
    unsigned short* __restrict__ Yh, unsigned short* __restrict__ Yl)
{
  const int tid = blockIdx.x * 256 + threadIdx.x;
  const int k8 = tid & 127, r = tid >> 7;
  const int c0 = k8 << 3;
  const int h = c0 >> 6, d0 = c0 & 63;
  const float* ya = y_att + ((size_t)(h * T_DIM + r) << 6) + d0;
  const float* ga = gate + ((size_t)r << 10) + c0;
  float4 y0 = *(const float4*)ya;
  float4 y1 = *(const float4*)(ya + 4);
  float4 g0 = *(const float4*)ga;
  float4 g1 = *(const float4*)(ga + 4);
  float p[8] = {y0.x * g0.x, y0.y * g0.y, y0.z * g0.z, y0.w * g0.w,
                y1.x * g1.x, y1.y * g1.y, y1.z * g1.z, y1.w * g1.w};
  unsigned hi[8], lo[8];
#pragma unroll
  for (int jj = 0; jj < 8; ++jj) {
    unsigned short hb = bf16rn(p[jj]);
    hi[jj] = hb;
    lo[jj] = bf16rn(p[jj] - __uint_as_float((unsigned)hb << 16));
  }
  const int t16 = r >> 4, rr = r & 15, kc = k8 >> 2, kq = k8 & 3;
  const size_t elem = (((size_t)(t16 * 32 + kc)) * 64 + ((kq << 4) | rr)) * 8;
  uint4 vh, vl;
  vh.x = hi[0] | (hi[1] << 16); vh.y = hi[2] | (hi[3] << 16);
  vh.z = hi[4] | (hi[5] << 16); vh.w = hi[6] | (hi[7] << 16);
  vl.x = lo[0] | (lo[1] << 16); vl.y = lo[2] | (lo[3] << 16);
  vl.z = lo[4] | (lo[5] << 16); vl.w = lo[6] | (lo[7] << 16);
  *(uint4*)(Yh + elem) = vh;
  *(uint4*)(Yl + elem) = vl;
}

extern "C" void kernel_launch(void* const* d_in, const int* in_sizes, int n_in,
                              void* d_out, int out_size, void* d_ws, size_t ws_size,
                              hipStream_t stream) {
  (void)in_sizes; (void)n_in; (void)out_size; (void)ws_size;
  const float* x           = (const float*)d_in[0];
  const float* w_attn      = (const float*)d_in[1];
  const float* w_proj      = (const float*)d_in[2];
  const float* w_gate      = (const float*)d_in[3];
  const float* span_params = (const float*)d_in[4];
  float* out = (float*)d_out;

  char* ws = (char*)d_ws;
  const size_t MB = 1024 * 1024;
  float* q     = (float*)(ws);            // 8 MB (qfrag; P0 after attn)
  float* k     = (float*)(ws + 8 * MB);   // 8 MB (kfrag; P1 after attn)
  float* v     = (float*)(ws + 16 * MB);  // 8 MB
  float* gate  = (float*)(ws + 24 * MB);  // 8 MB
  float* y_att = (float*)(ws + 32 * MB);  // 8 MB
  unsigned short* xf_h  = (unsigned short*)(ws + 40 * MB);  // 4 MB
  unsigned short* xf_l  = (unsigned short*)(ws + 44 * MB);  // 4 MB
  unsigned short* wqg_h = (unsigned short*)(ws + 48 * MB);  // 8 MB (w_attn+w_gate)
  unsigned short* wqg_l = (unsigned short*)(ws + 56 * MB);  // 8 MB
  unsigned short* wfp_h = (unsigned short*)(ws + 64 * MB);  // 2 MB
  unsigned short* wfp_l = (unsigned short*)(ws + 66 * MB);  // 2 MB
  unsigned short* ygf_h = (unsigned short*)(ws + 68 * MB);  // 4 MB
  unsigned short* ygf_l = (unsigned short*)(ws + 72 * MB);  // 4 MB
  float* P0 = q;   // q/k frag regions dead after attn
  float* P1 = k;

  // all four fp32->hi/lo frag converts in one launch
  convert_all_kernel<<<3584, 256, 0, stream>>>(
      x, w_attn, w_gate, w_proj, xf_h, xf_l, wqg_h, wqg_l, wfp_h, wfp_l);
  // fused qkv+gate GEMM (N=4096), silu epilogue on gate quadrant
  mgemm_qkvg_kernel<<<dim3(32, 16), 256, 0, stream>>>(
      xf_h, xf_l, wqg_h, wqg_l, q, k, v, gate);
  // RoPE + split -> attention frag layout, in place on q and k
  prep_frag_kernel<<<dim3(T_DIM / 16, H_DIM, 2), 64, 0, stream>>>(q, k);
  // attention
  attn_kernel<<<dim3(T_DIM / QTILE, H_DIM), 256, 0, stream>>>(
      q, k, v, span_params, y_att);
  // gating -> frag-global hi/lo
  gate_mul_frag_kernel<<<T_DIM / 2, 256, 0, stream>>>(y_att, gate, ygf_h, ygf_l);
  // proj GEMM, split-K x2 in one dispatch, then reduce
  mgemm_proj_kernel<<<dim3(8, 16, 2), 256, 0, stream>>>(
      ygf_h, ygf_l, wfp_h, wfp_l, P0, P1);
  add2_kernel<<<(T_DIM * C_DIM) / 1024, 256, 0, stream>>>(P0, P1, out);
}